// Round 8
// baseline (397.091 us; speedup 1.0000x reference)
//
#include <hip/hip_runtime.h>
#include <hip/hip_bf16.h>

using bf16 = __hip_bfloat16;
using u16 = unsigned short;
typedef __attribute__((ext_vector_type(8))) short bf16x8;
typedef __attribute__((ext_vector_type(16))) float f32x16;

namespace {

constexpr int B_  = 1024;
constexpr int Sd  = 100;
constexpr int BS_ = B_ * Sd;

constexpr int NTHR = 1024;   // 16 waves -> 4 waves/SIMD
constexpr int NW   = 16;

constexpr int STP = 420;   // ST q-row pitch; 2-way bank alias (free)
constexpr int STS = 104;   // per-stream pitch inside a q-row
constexpr int QKP = 196;   // QC/KC pitch
constexpr int AP  = 132;   // 128-wide staging pitch
constexpr int ATP = 68;    // 64-wide attr staging pitch
constexpr int VTP = 116;   // VT LDS pitch
constexpr int W1P = 116;   // fallback-only LDS W1T pitch

// PREP LDS arena (162,400 B)
constexpr int O_ST  = 0;       // ST [100][420] = 84,000 B
constexpr int O_SA0 = 0;       // SA0 [100][132] = 26,400 (input)
constexpr int O_SA1 = 26400;   // SA1 [100][132] = 26,400 (pos)
constexpr int O_AT0 = 52800;   // [100][68] = 13,600
constexpr int O_AT1 = 66400;   // ends 80,000 <= 84,000
constexpr int O_Q   = 84000;   // QC [100][196] = 39,200 (later VA [100][132])
constexpr int O_K   = 123200;  // KC [100][196] = 39,200 (later VT + e2s)
constexpr int O_VT  = 123200;  // VT [64][116] = 14,848
constexpr int O_E2S = 139200;  // e2s f32[400] = 1,600 (ends 140,800)
constexpr int LBYTES = 162400;

// d_ws bf16 blob element offsets (prep_weights layout)
constexpr int WQT_E  = 0;        // [2h][64c][128k]
constexpr int WKT_E  = 16384;
constexpr int WQPT_E = 32768;
constexpr int WKPT_E = 49152;
constexpr int WVT_E  = 65536;
constexpr int WAT_E  = 81920;    // [4pr][2h][32c][64k]
constexpr int W1T_E  = 98304;    // [128c][112k] incl. zero pads
constexpr int WDT_E  = 112640;   // [128c][128k]
constexpr int W1PG   = 112;      // global W1T pitch
constexpr size_t WS_NEED = 129024ull * 2;  // 258,048 B

__device__ __forceinline__ float bfr(u16 u) {
  unsigned int x = ((unsigned int)u) << 16;
  float f; __builtin_memcpy(&f, &x, 4); return f;
}
__device__ __forceinline__ u16 f2bu(float x) {
  bf16 h = __float2bfloat16(x);
  u16 u; __builtin_memcpy(&u, &h, 2); return u;
}
__device__ __forceinline__ float4 ld4(const float* p) {
  return *reinterpret_cast<const float4*>(p);
}
__device__ __forceinline__ float wsum(float v) {
#pragma unroll
  for (int m = 32; m > 0; m >>= 1) v += __shfl_xor(v, m);
  return v;
}
__device__ __forceinline__ float wmax(float v) {
#pragma unroll
  for (int m = 32; m > 0; m >>= 1) v = fmaxf(v, __shfl_xor(v, m));
  return v;
}
__device__ __forceinline__ f32x16 zf16() {
  f32x16 z;
#pragma unroll
  for (int i = 0; i < 16; ++i) z[i] = 0.f;
  return z;
}
__device__ __forceinline__ f32x16 MFMA32(bf16x8 a, bf16x8 b, f32x16 c) {
  return __builtin_amdgcn_mfma_f32_32x32x16_bf16(a, b, c, 0, 0, 0);
}

// 8 contiguous bf16, 8B-aligned (LDS): two b64 reads. Same helper for A and B
// operands -> any k-permutation inside the 16-block cancels in the MFMA.
__device__ __forceinline__ bf16x8 ld8(const u16* p) {
  const ushort4 a = *reinterpret_cast<const ushort4*>(p);
  const ushort4 b = *reinterpret_cast<const ushort4*>(p + 4);
  bf16x8 f;
  f[0] = (short)a.x; f[1] = (short)a.y; f[2] = (short)a.z; f[3] = (short)a.w;
  f[4] = (short)b.x; f[5] = (short)b.y; f[6] = (short)b.z; f[7] = (short)b.w;
  return f;
}
// 16B-aligned variant (global weight frags): single dwordx4
__device__ __forceinline__ bf16x8 ld8a(const u16* p) {
  return *reinterpret_cast<const bf16x8*>(p);
}

// global f32 rows (contiguous, ncol = 4<<L4) -> LDS bf16 [nrow][pitch]
template <int L4>
__device__ __forceinline__ void stage_rows4(const float* __restrict__ src, u16* dst,
                                            int nrow, int pitch, int tid, int nthr) {
  for (int i = tid; i < (nrow << L4); i += nthr) {
    const int rr = i >> L4, cc = (i & ((1 << L4) - 1)) << 2;
    const float4 v = *reinterpret_cast<const float4*>(src + ((size_t)rr << (L4 + 2)) + cc);
    ushort4 o;
    o.x = f2bu(v.x); o.y = f2bu(v.y); o.z = f2bu(v.z); o.w = f2bu(v.w);
    *reinterpret_cast<ushort4*>(dst + rr * pitch + cc) = o;
  }
}
// W[k][coff+c] -> WT[c][k] bf16 (fallback path only)
template <int LC>
__device__ __forceinline__ void stage_wt(const float* __restrict__ W, int ldw, int coff,
                                         u16* dst, int kd, int pitch, int tid, int nthr) {
  constexpr int NC = 1 << LC;
  for (int idx = tid; idx < NC * kd; idx += nthr) {
    const int k = idx >> LC, c = idx & (NC - 1);
    dst[c * pitch + k] = f2bu(W[k * ldw + coff + c]);
  }
}
__device__ __forceinline__ void stage_wt6(const float* __restrict__ W, int coff,
                                          u16* dst, int tid, int nthr) {
  stage_wt<6>(W, 128, coff, dst, 128, AP, tid, nthr);
}

// One 32x32 output tile: dst = A[100][KD] @ Wt[N][KD]^T + bias.
// GB: B operand is 16B-aligned global. TR: transposed store.
template <int KD, bool TR, bool GB>
__device__ __forceinline__ void tile32(const u16* A, int apitch, const u16* Wt, int wpitch,
                                       const float* __restrict__ bias, u16* dst, int dpitch,
                                       int dbase, int m0, int n0, int l) {
  const int cr = l & 31, g = l >> 5;
  int ar = m0 + cr; if (ar >= Sd) ar = Sd - 1;
  const u16* ap = A + ar * apitch + g * 8;
  const u16* bp = Wt + (n0 + cr) * wpitch + g * 8;
  f32x16 acc = zf16();
#pragma unroll
  for (int k0 = 0; k0 < KD; k0 += 16)
    acc = MFMA32(ld8(ap + k0), GB ? ld8a(bp + k0) : ld8(bp + k0), acc);
  const float bvv = bias[n0 + cr];
#pragma unroll
  for (int i = 0; i < 16; ++i) {
    const int row = m0 + (i & 3) + 8 * (i >> 2) + 4 * g;  // C/D: col=lane&31 (measured)
    if (row < Sd) {
      if (TR) dst[(n0 + cr) * dpitch + dbase + row] = f2bu(acc[i] + bvv);
      else    dst[row * dpitch + dbase + n0 + cr]   = f2bu(acc[i] + bvv);
    }
  }
}

// ---------------------------------------------------------------------------
// Weight preprocessing: f32 global -> bf16 transposed/padded blobs in d_ws.
// ---------------------------------------------------------------------------
__global__ __launch_bounds__(256) void prep_weights(
    const float* __restrict__ Wq, const float* __restrict__ Wk,
    const float* __restrict__ Wqp, const float* __restrict__ Wkp,
    const float* __restrict__ Wv, const float* __restrict__ Wqa,
    const float* __restrict__ Wka, const float* __restrict__ W1,
    const float* __restrict__ Wd, u16* __restrict__ ws) {
  const int t = blockIdx.x * 256 + threadIdx.x;
  const int NT = gridDim.x * 256;
  const float* srcs[5] = {Wq, Wk, Wqp, Wkp, Wv};
#pragma unroll
  for (int wsel = 0; wsel < 5; ++wsel) {
    u16* dst = ws + wsel * 16384;
    const float* src = srcs[wsel];
    for (int i = t; i < 16384; i += NT) {
      const int h = i >> 13, c = (i >> 7) & 63, k = i & 127;
      dst[i] = f2bu(src[k * 128 + h * 64 + c]);
    }
  }
  for (int i = t; i < 16384; i += NT) {
    const int pr = i >> 12, h = (i >> 11) & 1, c = (i >> 6) & 31, k = i & 63;
    const float* src = (pr & 1) ? Wka : Wqa;
    ws[WAT_E + i] = f2bu(src[(pr >> 1) * 4096 + k * 64 + h * 32 + c]);
  }
  for (int i = t; i < 14336; i += NT) {
    const int c = i / W1PG, k = i - c * W1PG;
    ws[W1T_E + i] = (c < Sd && k < Sd) ? f2bu(W1[k * Sd + c]) : (u16)0;
  }
  for (int i = t; i < 16384; i += NT) {
    const int c = i >> 7, k = i & 127;
    ws[WDT_E + i] = f2bu(Wd[k * 128 + c]);
  }
}

// ---------------------------------------------------------------------------
// PREP mega-kernel: weights as global B-frags, fused phases, wave-split P6/G7.
// ---------------------------------------------------------------------------
__global__ __launch_bounds__(NTHR) void attn_mega_p(
    const float* __restrict__ input, const float* __restrict__ attrT,
    const float* __restrict__ posE, const float* __restrict__ mask,
    const float* __restrict__ bq, const float* __restrict__ bk,
    const float* __restrict__ bv, const float* __restrict__ bqp,
    const float* __restrict__ bkp, const float* __restrict__ bqa,
    const float* __restrict__ bka, const float* __restrict__ b1,
    const float* __restrict__ W2, const u16* __restrict__ wsw,
    float* __restrict__ ctx) {
  __shared__ __align__(16) char L[LBYTES];
  u16* const ST  = (u16*)(L + O_ST);
  u16* const SA0 = (u16*)(L + O_SA0);
  u16* const SA1 = (u16*)(L + O_SA1);
  u16* const AT0 = (u16*)(L + O_AT0);
  u16* const AT1 = (u16*)(L + O_AT1);
  u16* const QC  = (u16*)(L + O_Q);
  u16* const KC  = (u16*)(L + O_K);
  u16* const VA  = (u16*)(L + O_Q);    // after G4 (QC dead)
  u16* const VT  = (u16*)(L + O_VT);   // after G4 (KC dead)
  float* const e2s = (float*)(L + O_E2S);

  const int tid = threadIdx.x;
  const int bh = blockIdx.x;
  const int b = bh >> 1, h = bh & 1;
  const size_t row0 = (size_t)b * Sd;
  const int l = tid & 63, w = tid >> 6;
  const int cr = l & 31, g = l >> 5;

  // ---------- S1: input -> SA0; prefetch pos ----------
  stage_rows4<5>(input + row0 * 128, SA0, 100, AP, tid, NTHR);
  float4 r2[4];
#pragma unroll
  for (int s = 0; s < 4; ++s) {
    const int fi = tid + s * NTHR;
    if (fi < 3200) r2[s] = ld4(posE + row0 * 128 + fi * 4);
  }
  __syncthreads();

  // ---------- G1: Q/K proj (global W) || prefetch attr || pos -> SA1 ----------
  float4 r3[4];
#pragma unroll
  for (int s = 0; s < 4; ++s) {
    const int fi = tid + s * NTHR;
    if (fi < 1600)      r3[s] = ld4(attrT + (size_t)b * 6400 + fi * 4);
    else if (fi < 3200) r3[s] = ld4(attrT + (size_t)(B_ + b) * 6400 + (fi - 1600) * 4);
  }
#pragma unroll
  for (int s = 0; s < 4; ++s) {
    const int fi = tid + s * NTHR;
    if (fi < 3200) {
      ushort4 o;
      o.x = f2bu(r2[s].x); o.y = f2bu(r2[s].y); o.z = f2bu(r2[s].z); o.w = f2bu(r2[s].w);
      *reinterpret_cast<ushort4*>(SA1 + (fi >> 5) * AP + ((fi & 31) << 2)) = o;
    }
  }
  {
    const int pr = w >> 3, mt = (w >> 1) & 3, nt = w & 1;
    const u16* wg = wsw + (pr ? WKT_E : WQT_E) + h * 8192;
    tile32<128, false, true>(SA0, AP, wg, 128, (pr ? bk : bq) + h * 64,
                             pr ? KC : QC, QKP, 0, mt * 32, nt * 32, l);
  }
  __syncthreads();

  // ---------- G2: QP/KP proj (reads SA1) || attr -> AT0/AT1 ----------
#pragma unroll
  for (int s = 0; s < 4; ++s) {
    const int fi = tid + s * NTHR;
    if (fi < 1600) {
      ushort4 o;
      o.x = f2bu(r3[s].x); o.y = f2bu(r3[s].y); o.z = f2bu(r3[s].z); o.w = f2bu(r3[s].w);
      *reinterpret_cast<ushort4*>(AT0 + (fi >> 4) * ATP + ((fi & 15) << 2)) = o;
    } else if (fi < 3200) {
      const int f3 = fi - 1600;
      ushort4 o;
      o.x = f2bu(r3[s].x); o.y = f2bu(r3[s].y); o.z = f2bu(r3[s].z); o.w = f2bu(r3[s].w);
      *reinterpret_cast<ushort4*>(AT1 + (f3 >> 4) * ATP + ((f3 & 15) << 2)) = o;
    }
  }
  {
    const int pr = w >> 3, mt = (w >> 1) & 3, nt = w & 1;
    const u16* wg = wsw + (pr ? WKPT_E : WQPT_E) + h * 8192;
    tile32<128, false, true>(SA1, AP, wg, 128, (pr ? bkp : bqp) + h * 64,
                             pr ? KC : QC, QKP, 64, mt * 32, nt * 32, l);
  }
  __syncthreads();

  // ---------- G3: attr projections (global W) ----------
  {
    const int pr = w >> 2, mt = w & 3;  // 0=A0Q 1=A0K 2=A1Q 3=A1K
    const u16* Asrc = (pr < 2) ? AT0 : AT1;
    const u16* wg = wsw + WAT_E + pr * 4096 + h * 2048;
    const float* bs = (pr == 0) ? bqa + h * 32 : (pr == 1) ? bka + h * 32
                     : (pr == 2) ? bqa + 64 + h * 32 : bka + 64 + h * 32;
    tile32<64, false, true>(Asrc, ATP, wg, 64, bs, (pr & 1) ? KC : QC, QKP,
                            128 + (pr >> 1) * 32, mt * 32, 0, l);
  }
  __syncthreads();

  // ---------- G4: 4-stream scores -> ST (+ finite row pads 416..419) ----------
  {
    ushort4 z; z.x = z.y = z.z = z.w = 0;
    for (int q = tid; q < Sd; q += NTHR)
      *reinterpret_cast<ushort4*>(ST + q * STP + 416) = z;
  }
  {
    const int mt = w >> 2, nt = w & 3;
    const int m0 = mt * 32, n0 = nt * 32;
    int ar = m0 + cr; if (ar >= Sd) ar = Sd - 1;
    int br = n0 + cr; if (br >= Sd) br = Sd - 1;
    const u16* ap = QC + ar * QKP + g * 8;
    const u16* bp = KC + br * QKP + g * 8;
    f32x16 ai = zf16(), po = zf16(), a0 = zf16(), a1 = zf16();
    ai = MFMA32(ld8(ap + 0),   ld8(bp + 0),   ai);
    ai = MFMA32(ld8(ap + 16),  ld8(bp + 16),  ai);
    ai = MFMA32(ld8(ap + 32),  ld8(bp + 32),  ai);
    ai = MFMA32(ld8(ap + 48),  ld8(bp + 48),  ai);
    po = MFMA32(ld8(ap + 64),  ld8(bp + 64),  po);
    po = MFMA32(ld8(ap + 80),  ld8(bp + 80),  po);
    po = MFMA32(ld8(ap + 96),  ld8(bp + 96),  po);
    po = MFMA32(ld8(ap + 112), ld8(bp + 112), po);
    a0 = MFMA32(ld8(ap + 128), ld8(bp + 128), a0);
    a0 = MFMA32(ld8(ap + 144), ld8(bp + 144), a0);
    a1 = MFMA32(ld8(ap + 160), ld8(bp + 160), a1);
    a1 = MFMA32(ld8(ap + 176), ld8(bp + 176), a1);
    const int col = n0 + cr;
    if (col < STS) {  // also writes finite pads at cols 100..103
#pragma unroll
      for (int i = 0; i < 16; ++i) {
        const int row = m0 + (i & 3) + 8 * (i >> 2) + 4 * g;
        if (row < Sd) {
          u16* sp = ST + row * STP + col;
          sp[0]       = f2bu(a0[i]);   // attr0
          sp[STS]     = f2bu(a1[i]);   // attr1
          sp[2 * STS] = f2bu(ai[i]);   // item
          sp[3 * STS] = f2bu(po[i]);   // pos
        }
      }
    }
  }
  __syncthreads();

  // ---------- S6: VA (input re-stage, also covers G5's 4-elem A-spill) + VT zero ----------
  stage_rows4<5>(input + row0 * 128, VA, 100, AP, tid, NTHR);
  {
    ushort4 z; z.x = z.y = z.z = z.w = 0;
    for (int i2 = tid; i2 < 64 * VTP / 4; i2 += NTHR)
      *reinterpret_cast<ushort4*>(VT + i2 * 4) = z;
  }
  __syncthreads();

  // ---------- G5: gate GEMM (W1T global) -> raw logits e2s ----------
  {
    float b1v[4], w2v[4];
#pragma unroll
    for (int nt = 0; nt < 4; ++nt) {
      const int c = nt * 32 + cr;
      b1v[nt] = (c < Sd) ? b1[c] : 0.f;
      w2v[nt] = (c < Sd) ? W2[c] : 0.f;
    }
    const u16* wg1 = wsw + W1T_E;
    for (int mt = w; mt < 13; mt += NW) {
      const int m0 = mt * 32;
      int gr = m0 + cr; if (gr > 399) gr = 399;
      const u16* ap = ST + (gr >> 2) * STP + (gr & 3) * STS + g * 8;
      f32x16 c0 = zf16(), c1 = zf16(), c2 = zf16(), c3 = zf16();
#pragma unroll
      for (int k0 = 0; k0 < 112; k0 += 16) {
        const bf16x8 af = ld8(ap + k0);
        c0 = MFMA32(af, ld8a(wg1 + (cr)      * W1PG + g * 8 + k0), c0);
        c1 = MFMA32(af, ld8a(wg1 + (32 + cr) * W1PG + g * 8 + k0), c1);
        c2 = MFMA32(af, ld8a(wg1 + (64 + cr) * W1PG + g * 8 + k0), c2);
        c3 = MFMA32(af, ld8a(wg1 + (96 + cr) * W1PG + g * 8 + k0), c3);
      }
#pragma unroll
      for (int i = 0; i < 16; ++i) {
        float v = fmaxf(c0[i] + b1v[0], 0.f) * w2v[0]
                + fmaxf(c1[i] + b1v[1], 0.f) * w2v[1]
                + fmaxf(c2[i] + b1v[2], 0.f) * w2v[2]
                + fmaxf(c3[i] + b1v[3], 0.f) * w2v[3];
#pragma unroll
        for (int mm = 1; mm < 32; mm <<= 1) v += __shfl_xor(v, mm);
        if (cr == 0) {
          const int go = m0 + (i & 3) + 8 * (i >> 2) + 4 * g;
          if (go < 400) e2s[go] = v;
        }
      }
    }
  }
  __syncthreads();

  // ---------- P6 (waves 0-7) softmax || G7 (waves 8-15) V projection ----------
  if (w < 8) {
    for (int q = w; q < Sd; q += 8) {
      const float* ez = e2s + q * 4;
      float e0 = ez[0], e1 = ez[1], e2v = ez[2], e3 = ez[3];
      const float mg = fmaxf(fmaxf(e0, e1), fmaxf(e2v, e3));
      e0 = __expf(e0 - mg); e1 = __expf(e1 - mg);
      e2v = __expf(e2v - mg); e3 = __expf(e3 - mg);
      const float ginv = 1.0f / (e0 + e1 + e2v + e3);
      const float g0v = e0 * ginv, g1v = e1 * ginv, g2v = e2v * ginv, g3v = e3 * ginv;
      u16* const sp = ST + q * STP;
      const float* const mp = mask + (size_t)b * 10000 + q * 100;
      float x1 = g0v * bfr(sp[l]) + g1v * bfr(sp[STS + l]) +
                 g2v * bfr(sp[2 * STS + l]) + g3v * bfr(sp[3 * STS + l]);
      x1 = x1 * 0.125f + mp[l];
      const bool v2 = (l < 36);
      float x2 = -3e38f;
      if (v2) {
        const int k2 = 64 + l;
        x2 = g0v * bfr(sp[k2]) + g1v * bfr(sp[STS + k2]) +
             g2v * bfr(sp[2 * STS + k2]) + g3v * bfr(sp[3 * STS + k2]);
        x2 = x2 * 0.125f + mp[k2];
      }
      const float M = wmax(fmaxf(x1, x2));
      const float ea = __expf(x1 - M);
      const float eb = v2 ? __expf(x2 - M) : 0.f;
      const float inv = 1.0f / wsum(ea + eb);
      sp[l] = f2bu(ea * inv);
      if (v2) sp[64 + l] = f2bu(eb * inv);
    }
  } else {
    const int u = w - 8;
    const int mt = u >> 1, nt = u & 1;
    tile32<128, true, true>(VA, AP, wsw + WVT_E + h * 8192, 128, bv + h * 64,
                            VT, VTP, 0, mt * 32, nt * 32, l);
  }
  __syncthreads();

  // ---------- G8: PV -> ctx (global f32) ----------
  if (w < 8) {
    const int mt = w >> 1, nt = w & 1;
    const int m0 = mt * 32, n0 = nt * 32;
    int ar = m0 + cr; if (ar >= Sd) ar = Sd - 1;
    const u16* ap = ST + ar * STP + g * 8;
    const u16* bp = VT + (n0 + cr) * VTP + g * 8;
    f32x16 acc = zf16();
#pragma unroll
    for (int k0 = 0; k0 < 112; k0 += 16)
      acc = MFMA32(ld8(ap + k0), ld8(bp + k0), acc);
#pragma unroll
    for (int i = 0; i < 16; ++i) {
      const int row = m0 + (i & 3) + 8 * (i >> 2) + 4 * g;
      if (row < Sd)
        ctx[(row0 + row) * 128 + h * 64 + n0 + cr] = acc[i];
    }
  }
}

// ---------------------------------------------------------------------------
// PREP dense+LN: Wd frags from global; LDS 67.6 KB -> 2 blocks/CU.
// ---------------------------------------------------------------------------
__global__ __launch_bounds__(512, 4) void dense_ln_p(
    const float* __restrict__ ctxg, const float* __restrict__ bd,
    const float* __restrict__ resid, const float* __restrict__ lng,
    const float* __restrict__ lnb, const u16* __restrict__ wsw,
    float* __restrict__ out) {
  __shared__ __align__(16) char L[67584];
  u16* const Ab = (u16*)L;              // [128][132]
  u16* const Hs = (u16*)(L + 33792);    // [128][132] bf16 (GEMM term only)
  const int tid = threadIdx.x;
  const size_t row0 = (size_t)blockIdx.x * 128;
  const int l = tid & 63, w = tid >> 6, cr = l & 31, g = l >> 5;

  stage_rows4<5>(ctxg + row0 * 128, Ab, 128, AP, tid, 512);
  __syncthreads();

  for (int u = w; u < 16; u += 8) {
    const int m0 = (u >> 2) * 32, n0 = (u & 3) * 32;
    const u16* ap = Ab + (m0 + cr) * AP + g * 8;
    const u16* bp = wsw + WDT_E + (n0 + cr) * 128 + g * 8;
    f32x16 acc = zf16();
#pragma unroll
    for (int k0 = 0; k0 < 128; k0 += 16)
      acc = MFMA32(ld8(ap + k0), ld8a(bp + k0), acc);
#pragma unroll
    for (int i = 0; i < 16; ++i) {
      const int row = m0 + (i & 3) + 8 * (i >> 2) + 4 * g;
      Hs[row * AP + n0 + cr] = f2bu(acc[i]);
    }
  }
  __syncthreads();

  for (int rr = w; rr < 128; rr += 8) {
    const size_t grow = row0 + rr;
    const float h1 = bfr(Hs[rr * AP + l])      + bd[l]      + resid[grow * 128 + l];
    const float h2 = bfr(Hs[rr * AP + 64 + l]) + bd[64 + l] + resid[grow * 128 + 64 + l];
    const float mu = wsum(h1 + h2) * (1.0f / 128.0f);
    const float d1 = h1 - mu, d2 = h2 - mu;
    const float var = wsum(d1 * d1 + d2 * d2) * (1.0f / 128.0f);
    const float rs = rsqrtf(var + 1e-12f);
    out[grow * 128 + l]      = d1 * rs * lng[l]      + lnb[l];
    out[grow * 128 + 64 + l] = d2 * rs * lng[64 + l] + lnb[64 + l];
  }
}

// ---------------------------------------------------------------------------
// Fallback kernels (Round-6 structure, no d_ws) — used only if ws too small.
// ---------------------------------------------------------------------------
__global__ __launch_bounds__(NTHR) void attn_mega_fb(
    const float* __restrict__ input, const float* __restrict__ attrT,
    const float* __restrict__ posE, const float* __restrict__ mask,
    const float* __restrict__ Wq, const float* __restrict__ bq,
    const float* __restrict__ Wk, const float* __restrict__ bk,
    const float* __restrict__ Wv, const float* __restrict__ bv,
    const float* __restrict__ Wqp, const float* __restrict__ bqp,
    const float* __restrict__ Wkp, const float* __restrict__ bkp,
    const float* __restrict__ Wqa, const float* __restrict__ bqa,
    const float* __restrict__ Wka, const float* __restrict__ bka,
    const float* __restrict__ W1, const float* __restrict__ b1,
    const float* __restrict__ W2, float* __restrict__ ctx) {
  __shared__ __align__(16) char L[LBYTES];
  u16* const ST = (u16*)(L + O_ST);
  u16* const QC = (u16*)(L + O_Q);
  u16* const KC = (u16*)(L + O_K);
  u16* const SA  = (u16*)(L + O_ST);
  u16* const SW1 = (u16*)(L + O_ST + 26400);
  u16* const SW2 = (u16*)(L + O_ST + 43296);
  u16* const AT0  = (u16*)(L + O_ST);
  u16* const AT1  = (u16*)(L + O_ST + 13600);
  u16* const WA0Q = (u16*)(L + O_ST + 27200);
  u16* const WA0K = (u16*)(L + O_ST + 31552);
  u16* const WA1Q = (u16*)(L + O_ST + 35904);
  u16* const WA1K = (u16*)(L + O_ST + 40256);
  u16* const W1T = (u16*)(L + O_K);
  float* const e2s = (float*)(L + O_K + 32000);
  u16* const VA  = (u16*)(L + O_Q);
  u16* const WVT = (u16*)(L + O_K);
  u16* const VT  = (u16*)(L + O_K + 16896);

  const int tid = threadIdx.x;
  const int bh = blockIdx.x;
  const int b = bh >> 1, h = bh & 1;
  const size_t row0 = (size_t)b * Sd;
  const int l = tid & 63, w = tid >> 6;
  const int cr = l & 31, g = l >> 5;

  stage_rows4<5>(input + row0 * 128, SA, 100, AP, tid, NTHR);
  stage_wt6(Wq, h * 64, SW1, tid, NTHR);
  stage_wt6(Wk, h * 64, SW2, tid, NTHR);
  float4 r2[8];
#pragma unroll
  for (int s = 0; s < 8; ++s) {
    const int fi = tid + s * NTHR;
    if (fi < 3200) r2[s] = ld4(posE + row0 * 128 + fi * 4);
    else if (fi < 5248) {
      const int f2 = fi - 3200, k = f2 >> 4, c0 = (f2 & 15) << 2;
      r2[s] = ld4(Wqp + k * 128 + h * 64 + c0);
    } else if (fi < 7296) {
      const int f2 = fi - 5248, k = f2 >> 4, c0 = (f2 & 15) << 2;
      r2[s] = ld4(Wkp + k * 128 + h * 64 + c0);
    }
  }
  __syncthreads();
  {
    const int pr = w >> 3, mt = (w >> 1) & 3, nt = w & 1;
    tile32<128, false, false>(SA, AP, pr ? SW2 : SW1, AP, (pr ? bk : bq) + h * 64,
                              pr ? KC : QC, QKP, 0, mt * 32, nt * 32, l);
  }
  __syncthreads();
#pragma unroll
  for (int s = 0; s < 8; ++s) {
    const int fi = tid + s * NTHR;
    if (fi < 3200) {
      ushort4 o;
      o.x = f2bu(r2[s].x); o.y = f2bu(r2[s].y); o.z = f2bu(r2[s].z); o.w = f2bu(r2[s].w);
      *reinterpret_cast<ushort4*>(SA + (fi >> 5) * AP + ((fi & 31) << 2)) = o;
    } else if (fi < 5248) {
      const int f2 = fi - 3200, k = f2 >> 4, c0 = (f2 & 15) << 2;
      SW1[c0 * AP + k] = f2bu(r2[s].x); SW1[(c0 + 1) * AP + k] = f2bu(r2[s].y);
      SW1[(c0 + 2) * AP + k] = f2bu(r2[s].z); SW1[(c0 + 3) * AP + k] = f2bu(r2[s].w);
    } else if (fi < 7296) {
      const int f2 = fi - 5248, k = f2 >> 4, c0 = (f2 & 15) << 2;
      SW2[c0 * AP + k] = f2bu(r2[s].x); SW2[(c0 + 1) * AP + k] = f2bu(r2[s].y);
      SW2[(c0 + 2) * AP + k] = f2bu(r2[s].z); SW2[(c0 + 3) * AP + k] = f2bu(r2[s].w);
    }
  }
  float4 r3[6];
#pragma unroll
  for (int s = 0; s < 6; ++s) {
    const int fi = tid + s * NTHR;
    if (fi < 1600) r3[s] = ld4(attrT + (size_t)b * 6400 + fi * 4);
    else if (fi < 3200) r3[s] = ld4(attrT + (size_t)(B_ + b) * 6400 + (fi - 1600) * 4);
    else if (fi < 5248) {
      const int f3 = fi - 3200, which = f3 >> 9, fj = f3 & 511;
      const int k = fj >> 3, c0 = (fj & 7) << 2;
      const float* src = (which == 0) ? Wqa : (which == 1) ? Wka
                       : (which == 2) ? (Wqa + 4096) : (Wka + 4096);
      r3[s] = ld4(src + k * 64 + h * 32 + c0);
    }
  }
  __syncthreads();
  {
    const int pr = w >> 3, mt = (w >> 1) & 3, nt = w & 1;
    tile32<128, false, false>(SA, AP, pr ? SW2 : SW1, AP, (pr ? bkp : bqp) + h * 64,
                              pr ? KC : QC, QKP, 64, mt * 32, nt * 32, l);
  }
  __syncthreads();
#pragma unroll
  for (int s = 0; s < 6; ++s) {
    const int fi = tid + s * NTHR;
    if (fi < 1600) {
      ushort4 o;
      o.x = f2bu(r3[s].x); o.y = f2bu(r3[s].y); o.z = f2bu(r3[s].z); o.w = f2bu(r3[s].w);
      *reinterpret_cast<ushort4*>(AT0 + (fi >> 4) * ATP + ((fi & 15) << 2)) = o;
    } else if (fi < 3200) {
      const int f3 = fi - 1600;
      ushort4 o;
      o.x = f2bu(r3[s].x); o.y = f2bu(r3[s].y); o.z = f2bu(r3[s].z); o.w = f2bu(r3[s].w);
      *reinterpret_cast<ushort4*>(AT1 + (f3 >> 4) * ATP + ((f3 & 15) << 2)) = o;
    } else if (fi < 5248) {
      const int f3 = fi - 3200, which = f3 >> 9, fj = f3 & 511;
      const int k = fj >> 3, c0 = (fj & 7) << 2;
      u16* dst = (which == 0) ? WA0Q : (which == 1) ? WA0K
               : (which == 2) ? WA1Q : WA1K;
      dst[c0 * ATP + k] = f2bu(r3[s].x); dst[(c0 + 1) * ATP + k] = f2bu(r3[s].y);
      dst[(c0 + 2) * ATP + k] = f2bu(r3[s].z); dst[(c0 + 3) * ATP + k] = f2bu(r3[s].w);
    }
  }
  float4 r5[3];
#pragma unroll
  for (int s = 0; s < 3; ++s) {
    const int fi = tid + s * NTHR;
    if (fi < 2500) r5[s] = ld4(W1 + fi * 4);
  }
  __syncthreads();
  {
    const int pr = w >> 2, mt = w & 3;
    const u16* Asrc = (pr < 2) ? AT0 : AT1;
    const u16* Wt = (pr == 0) ? WA0Q : (pr == 1) ? WA0K : (pr == 2) ? WA1Q : WA1K;
    const float* bs = (pr == 0) ? bqa + h * 32 : (pr == 1) ? bka + h * 32
                     : (pr == 2) ? bqa + 64 + h * 32 : bka + 64 + h * 32;
    tile32<64, false, false>(Asrc, ATP, Wt, ATP, bs, (pr & 1) ? KC : QC, QKP,
                             128 + (pr >> 1) * 32, mt * 32, 0, l);
  }
  __syncthreads();
  {
    ushort4 z; z.x = z.y = z.z = z.w = 0;
    for (int q = tid; q < Sd; q += NTHR)
      *reinterpret_cast<ushort4*>(ST + q * STP + 416) = z;
  }
  {
    const int mt = w >> 2, nt = w & 3;
    const int m0 = mt * 32, n0 = nt * 32;
    int ar = m0 + cr; if (ar >= Sd) ar = Sd - 1;
    int br = n0 + cr; if (br >= Sd) br = Sd - 1;
    const u16* ap = QC + ar * QKP + g * 8;
    const u16* bp = KC + br * QKP + g * 8;
    f32x16 ai = zf16(), po = zf16(), a0 = zf16(), a1 = zf16();
    ai = MFMA32(ld8(ap + 0),   ld8(bp + 0),   ai);
    ai = MFMA32(ld8(ap + 16),  ld8(bp + 16),  ai);
    ai = MFMA32(ld8(ap + 32),  ld8(bp + 32),  ai);
    ai = MFMA32(ld8(ap + 48),  ld8(bp + 48),  ai);
    po = MFMA32(ld8(ap + 64),  ld8(bp + 64),  po);
    po = MFMA32(ld8(ap + 80),  ld8(bp + 80),  po);
    po = MFMA32(ld8(ap + 96),  ld8(bp + 96),  po);
    po = MFMA32(ld8(ap + 112), ld8(bp + 112), po);
    a0 = MFMA32(ld8(ap + 128), ld8(bp + 128), a0);
    a0 = MFMA32(ld8(ap + 144), ld8(bp + 144), a0);
    a1 = MFMA32(ld8(ap + 160), ld8(bp + 160), a1);
    a1 = MFMA32(ld8(ap + 176), ld8(bp + 176), a1);
    const int col = n0 + cr;
    if (col < STS) {
#pragma unroll
      for (int i = 0; i < 16; ++i) {
        const int row = m0 + (i & 3) + 8 * (i >> 2) + 4 * g;
        if (row < Sd) {
          u16* sp = ST + row * STP + col;
          sp[0]       = f2bu(a0[i]);
          sp[STS]     = f2bu(a1[i]);
          sp[2 * STS] = f2bu(ai[i]);
          sp[3 * STS] = f2bu(po[i]);
        }
      }
    }
  }
  __syncthreads();
  {
    ushort4 z; z.x = z.y = z.z = z.w = 0;
    if (tid < 812)
      *reinterpret_cast<ushort4*>(W1T + 11600 + tid * 4) = z;
    if (tid < 400) {
      const int c = tid >> 2, kq = 100 + ((tid & 3) << 2);
      *reinterpret_cast<ushort4*>(W1T + c * W1P + kq) = z;
    }
  }
  if (tid < 8) ((u16*)(L + O_Q))[tid] = 0;
#pragma unroll
  for (int s = 0; s < 3; ++s) {
    const int fi = tid + s * NTHR;
    if (fi < 2500) {
#pragma unroll
      for (int j = 0; j < 4; ++j) {
        const int o = fi * 4 + j;
        const int k = o / 100, c = o - k * 100;
        W1T[c * W1P + k] = f2bu((j == 0) ? r5[s].x : (j == 1) ? r5[s].y
                                : (j == 2) ? r5[s].z : r5[s].w);
      }
    }
  }
  __syncthreads();
  {
    float b1v[4], w2v[4];
#pragma unroll
    for (int nt = 0; nt < 4; ++nt) {
      const int c = nt * 32 + cr;
      b1v[nt] = (c < Sd) ? b1[c] : 0.f;
      w2v[nt] = (c < Sd) ? W2[c] : 0.f;
    }
    for (int mt = w; mt < 13; mt += NW) {
      const int m0 = mt * 32;
      int gr = m0 + cr; if (gr > 399) gr = 399;
      const u16* ap = ST + (gr >> 2) * STP + (gr & 3) * STS + g * 8;
      f32x16 c0 = zf16(), c1 = zf16(), c2 = zf16(), c3 = zf16();
#pragma unroll
      for (int k0 = 0; k0 < 112; k0 += 16) {
        const bf16x8 af = ld8(ap + k0);
        c0 = MFMA32(af, ld8(W1T + (cr)      * W1P + g * 8 + k0), c0);
        c1 = MFMA32(af, ld8(W1T + (32 + cr) * W1P + g * 8 + k0), c1);
        c2 = MFMA32(af, ld8(W1T + (64 + cr) * W1P + g * 8 + k0), c2);
        c3 = MFMA32(af, ld8(W1T + (96 + cr) * W1P + g * 8 + k0), c3);
      }
#pragma unroll
      for (int i = 0; i < 16; ++i) {
        float v = fmaxf(c0[i] + b1v[0], 0.f) * w2v[0]
                + fmaxf(c1[i] + b1v[1], 0.f) * w2v[1]
                + fmaxf(c2[i] + b1v[2], 0.f) * w2v[2]
                + fmaxf(c3[i] + b1v[3], 0.f) * w2v[3];
#pragma unroll
        for (int mm = 1; mm < 32; mm <<= 1) v += __shfl_xor(v, mm);
        if (cr == 0) {
          const int go = m0 + (i & 3) + 8 * (i >> 2) + 4 * g;
          if (go < 400) e2s[go] = v;
        }
      }
    }
  }
  __syncthreads();
  stage_rows4<5>(input + row0 * 128, VA, 100, AP, tid, NTHR);
  stage_wt6(Wv, h * 64, WVT, tid, NTHR);
  {
    ushort4 z; z.x = z.y = z.z = z.w = 0;
    for (int i2 = tid; i2 < 64 * VTP / 4; i2 += NTHR)
      *reinterpret_cast<ushort4*>(VT + i2 * 4) = z;
  }
  for (int q = w; q < Sd; q += NW) {
    const float* ez = e2s + q * 4;
    float e0 = ez[0], e1 = ez[1], e2v = ez[2], e3 = ez[3];
    const float mg = fmaxf(fmaxf(e0, e1), fmaxf(e2v, e3));
    e0 = __expf(e0 - mg); e1 = __expf(e1 - mg);
    e2v = __expf(e2v - mg); e3 = __expf(e3 - mg);
    const float ginv = 1.0f / (e0 + e1 + e2v + e3);
    const float g0v = e0 * ginv, g1v = e1 * ginv, g2v = e2v * ginv, g3v = e3 * ginv;
    u16* const sp = ST + q * STP;
    const float* const mp = mask + (size_t)b * 10000 + q * 100;
    float x1 = g0v * bfr(sp[l]) + g1v * bfr(sp[STS + l]) +
               g2v * bfr(sp[2 * STS + l]) + g3v * bfr(sp[3 * STS + l]);
    x1 = x1 * 0.125f + mp[l];
    const bool v2 = (l < 36);
    float x2 = -3e38f;
    if (v2) {
      const int k2 = 64 + l;
      x2 = g0v * bfr(sp[k2]) + g1v * bfr(sp[STS + k2]) +
           g2v * bfr(sp[2 * STS + k2]) + g3v * bfr(sp[3 * STS + k2]);
      x2 = x2 * 0.125f + mp[k2];
    }
    const float M = wmax(fmaxf(x1, x2));
    const float ea = __expf(x1 - M);
    const float eb = v2 ? __expf(x2 - M) : 0.f;
    const float inv = 1.0f / wsum(ea + eb);
    sp[l] = f2bu(ea * inv);
    if (v2) sp[64 + l] = f2bu(eb * inv);
  }
  __syncthreads();
  if (w < 8) {
    const int mt = w >> 1, nt = w & 1;
    tile32<128, true, false>(VA, AP, WVT, AP, bv + h * 64, VT, VTP, 0, mt * 32, nt * 32, l);
  }
  __syncthreads();
  if (w < 8) {
    const int mt = w >> 1, nt = w & 1;
    const int m0 = mt * 32, n0 = nt * 32;
    int ar = m0 + cr; if (ar >= Sd) ar = Sd - 1;
    const u16* ap = ST + ar * STP + g * 8;
    const u16* bp = VT + (n0 + cr) * VTP + g * 8;
    f32x16 acc = zf16();
#pragma unroll
    for (int k0 = 0; k0 < 112; k0 += 16)
      acc = MFMA32(ld8(ap + k0), ld8(bp + k0), acc);
#pragma unroll
    for (int i = 0; i < 16; ++i) {
      const int row = m0 + (i & 3) + 8 * (i >> 2) + 4 * g;
      if (row < Sd)
        ctx[(row0 + row) * 128 + h * 64 + n0 + cr] = acc[i];
    }
  }
}

__global__ __launch_bounds__(512) void dense_ln_fb(
    const float* __restrict__ ctxg, const float* __restrict__ Wd,
    const float* __restrict__ bd, const float* __restrict__ resid,
    const float* __restrict__ lng, const float* __restrict__ lnb,
    float* __restrict__ out) {
  __shared__ __align__(16) char L[101376];
  u16* const Ab  = (u16*)L;
  u16* const WdT = (u16*)(L + 33792);
  u16* const Hs  = (u16*)(L + 67584);
  const int tid = threadIdx.x;
  const size_t row0 = (size_t)blockIdx.x * 128;
  const int l = tid & 63, w = tid >> 6, cr = l & 31, g = l >> 5;

  stage_rows4<5>(ctxg + row0 * 128, Ab, 128, AP, tid, 512);
  stage_wt<7>(Wd, 128, 0, WdT, 128, AP, tid, 512);
  __syncthreads();
  for (int u = w; u < 16; u += 8) {
    const int m0 = (u >> 2) * 32, n0 = (u & 3) * 32;
    const u16* ap = Ab + (m0 + cr) * AP + g * 8;
    const u16* bp = WdT + (n0 + cr) * AP + g * 8;
    f32x16 acc = zf16();
#pragma unroll
    for (int k0 = 0; k0 < 128; k0 += 16)
      acc = MFMA32(ld8(ap + k0), ld8(bp + k0), acc);
#pragma unroll
    for (int i = 0; i < 16; ++i) {
      const int row = m0 + (i & 3) + 8 * (i >> 2) + 4 * g;
      Hs[row * AP + n0 + cr] = f2bu(acc[i]);
    }
  }
  __syncthreads();
  for (int rr = w; rr < 128; rr += 8) {
    const size_t grow = row0 + rr;
    const float h1 = bfr(Hs[rr * AP + l])      + bd[l]      + resid[grow * 128 + l];
    const float h2 = bfr(Hs[rr * AP + 64 + l]) + bd[64 + l] + resid[grow * 128 + 64 + l];
    const float mu = wsum(h1 + h2) * (1.0f / 128.0f);
    const float d1 = h1 - mu, d2 = h2 - mu;
    const float var = wsum(d1 * d1 + d2 * d2) * (1.0f / 128.0f);
    const float rs = rsqrtf(var + 1e-12f);
    out[grow * 128 + l]      = d1 * rs * lng[l]      + lnb[l];
    out[grow * 128 + 64 + l] = d2 * rs * lng[64 + l] + lnb[64 + l];
  }
}

}  // namespace

extern "C" void kernel_launch(void* const* d_in, const int* in_sizes, int n_in,
                              void* d_out, int out_size, void* d_ws,
                              size_t ws_size, hipStream_t stream) {
  (void)in_sizes; (void)n_in; (void)out_size;

  const float* input = (const float*)d_in[0];
  const float* attrT = (const float*)d_in[1];
  const float* posE  = (const float*)d_in[2];
  const float* mask  = (const float*)d_in[3];
  const float* Wq  = (const float*)d_in[4];  const float* bq  = (const float*)d_in[5];
  const float* Wk  = (const float*)d_in[6];  const float* bk  = (const float*)d_in[7];
  const float* Wv  = (const float*)d_in[8];  const float* bv  = (const float*)d_in[9];
  const float* Wqp = (const float*)d_in[10]; const float* bqp = (const float*)d_in[11];
  const float* Wkp = (const float*)d_in[12]; const float* bkp = (const float*)d_in[13];
  const float* Wqa = (const float*)d_in[14]; const float* bqa = (const float*)d_in[15];
  const float* Wka = (const float*)d_in[16]; const float* bka = (const float*)d_in[17];
  const float* W1  = (const float*)d_in[18]; const float* b1  = (const float*)d_in[19];
  const float* W2  = (const float*)d_in[20];
  const float* Wd  = (const float*)d_in[22]; const float* bd  = (const float*)d_in[23];
  const float* lng = (const float*)d_in[24]; const float* lnb = (const float*)d_in[25];

  float* ctx = (float*)d_out;  // d_out doubles as ctx staging, then final output

  if (ws_size >= WS_NEED) {
    u16* wsw = (u16*)d_ws;
    prep_weights<<<dim3(128), dim3(256), 0, stream>>>(
        Wq, Wk, Wqp, Wkp, Wv, Wqa, Wka, W1, Wd, wsw);
    attn_mega_p<<<dim3(B_ * 2), dim3(NTHR), 0, stream>>>(
        input, attrT, posE, mask, bq, bk, bv, bqp, bkp, bqa, bka, b1, W2, wsw, ctx);
    dense_ln_p<<<dim3(BS_ / 128), dim3(512), 0, stream>>>(
        ctx, bd, input, lng, lnb, wsw, ctx);
  } else {
    attn_mega_fb<<<dim3(B_ * 2), dim3(NTHR), 0, stream>>>(
        input, attrT, posE, mask, Wq, bq, Wk, bk, Wv, bv, Wqp, bqp, Wkp, bkp,
        Wqa, bqa, Wka, bka, W1, b1, W2, ctx);
    dense_ln_fb<<<dim3(BS_ / 128), dim3(512), 0, stream>>>(
        ctx, Wd, bd, input, lng, lnb, ctx);
  }
}

// Round 9
// 359.565 us; speedup vs baseline: 1.1044x; 1.1044x over previous
//
#include <hip/hip_runtime.h>
#include <hip/hip_bf16.h>

using bf16 = __hip_bfloat16;
using u16 = unsigned short;
typedef __attribute__((ext_vector_type(8))) short bf16x8;
typedef __attribute__((ext_vector_type(16))) float f32x16;

namespace {

constexpr int B_  = 1024;
constexpr int Sd  = 100;
constexpr int BS_ = B_ * Sd;

constexpr int NTHR = 1024;   // 16 waves -> 4 waves/SIMD
constexpr int NW   = 16;

constexpr int STP = 420;   // ST q-row pitch; 2-way bank alias (free)
constexpr int STS = 104;   // per-stream pitch inside a q-row
constexpr int QKP = 196;   // QC/KC pitch
constexpr int AP  = 132;   // 128-wide staging pitch
constexpr int ATP = 68;    // 64-wide attr staging pitch
constexpr int W1P = 116;   // W1T pitch (112 would be 8-way conflict)
constexpr int VTP = 116;

constexpr int O_ST = 0;        // ST [100][420] = 84,000 B (P1-P3: staging scratch)
constexpr int O_Q  = 84000;    // QC [100][196] = 39,200 (S5+: VA [100][132])
constexpr int O_K  = 123200;   // KC [100][196] = 39,200 (G5: W1T+e2s; SPLIT: VT+e2s)
constexpr int E2S  = 32000;    // e2s f32[400] at O_K+32000 (> VT end 31,744; > W1T end 29,696)
constexpr int LBYTES = 162400;

// d_ws bf16 blob element offsets (prep_weights layout)
constexpr int WQT_E  = 0;        // [2h][64c][128k]
constexpr int WKT_E  = 16384;
constexpr int WQPT_E = 32768;
constexpr int WKPT_E = 49152;
constexpr int WVT_E  = 65536;
constexpr int WAT_E  = 81920;    // [4pr][2h][32c][64k]
constexpr int W1T_E  = 98304;    // [128c][116k] incl. zero pads
constexpr int WDT_E  = 113152;   // [128c][128k]
constexpr size_t WS_NEED = 129536ull * 2;  // 259,072 B

__device__ __forceinline__ float bfr(u16 u) {
  unsigned int x = ((unsigned int)u) << 16;
  float f; __builtin_memcpy(&f, &x, 4); return f;
}
__device__ __forceinline__ u16 f2bu(float x) {
  bf16 h = __float2bfloat16(x);
  u16 u; __builtin_memcpy(&u, &h, 2); return u;
}
__device__ __forceinline__ float4 ld4(const float* p) {
  return *reinterpret_cast<const float4*>(p);
}
__device__ __forceinline__ float wsum(float v) {
#pragma unroll
  for (int m = 32; m > 0; m >>= 1) v += __shfl_xor(v, m);
  return v;
}
__device__ __forceinline__ float wmax(float v) {
#pragma unroll
  for (int m = 32; m > 0; m >>= 1) v = fmaxf(v, __shfl_xor(v, m));
  return v;
}
__device__ __forceinline__ f32x16 zf16() {
  f32x16 z;
#pragma unroll
  for (int i = 0; i < 16; ++i) z[i] = 0.f;
  return z;
}
__device__ __forceinline__ f32x16 MFMA32(bf16x8 a, bf16x8 b, f32x16 c) {
  return __builtin_amdgcn_mfma_f32_32x32x16_bf16(a, b, c, 0, 0, 0);
}

// 8 contiguous bf16, 8B-aligned (LDS): two b64 reads. Same helper for A and B
// operands -> any k-permutation inside the 16-block cancels in the MFMA.
__device__ __forceinline__ bf16x8 ld8(const u16* p) {
  const ushort4 a = *reinterpret_cast<const ushort4*>(p);
  const ushort4 b = *reinterpret_cast<const ushort4*>(p + 4);
  bf16x8 f;
  f[0] = (short)a.x; f[1] = (short)a.y; f[2] = (short)a.z; f[3] = (short)a.w;
  f[4] = (short)b.x; f[5] = (short)b.y; f[6] = (short)b.z; f[7] = (short)b.w;
  return f;
}
// 16B-aligned variant (global weight frags)
__device__ __forceinline__ bf16x8 ld8a(const u16* p) {
  return *reinterpret_cast<const bf16x8*>(p);
}

// global f32 rows (contiguous, ncol = 4<<L4) -> LDS bf16 [nrow][pitch]
template <int L4>
__device__ __forceinline__ void stage_rows4(const float* __restrict__ src, u16* dst,
                                            int nrow, int pitch, int tid, int nthr) {
  for (int i = tid; i < (nrow << L4); i += nthr) {
    const int rr = i >> L4, cc = (i & ((1 << L4) - 1)) << 2;
    const float4 v = *reinterpret_cast<const float4*>(src + ((size_t)rr << (L4 + 2)) + cc);
    ushort4 o;
    o.x = f2bu(v.x); o.y = f2bu(v.y); o.z = f2bu(v.z); o.w = f2bu(v.w);
    *reinterpret_cast<ushort4*>(dst + rr * pitch + cc) = o;
  }
}
// W[k][coff+c] -> WT[c][k] bf16 (fallback path only)
template <int LC>
__device__ __forceinline__ void stage_wt(const float* __restrict__ W, int ldw, int coff,
                                         u16* dst, int kd, int pitch, int tid, int nthr) {
  constexpr int NC = 1 << LC;
  for (int idx = tid; idx < NC * kd; idx += nthr) {
    const int k = idx >> LC, c = idx & (NC - 1);
    dst[c * pitch + k] = f2bu(W[k * ldw + coff + c]);
  }
}
__device__ __forceinline__ void stage_wt6(const float* __restrict__ W, int coff,
                                          u16* dst, int tid, int nthr) {
  stage_wt<6>(W, 128, coff, dst, 128, AP, tid, nthr);
}
// ws bf16 [64][128] blob -> LDS [64][AP] (vectorized copy)
__device__ __forceinline__ void copy_w64(const u16* __restrict__ src, u16* dst,
                                         int tid, int nthr) {
  for (int i = tid; i < 2048; i += nthr) {
    const int r = i >> 5, c4 = (i & 31) << 2;
    *reinterpret_cast<ushort4*>(dst + r * AP + c4) =
        *reinterpret_cast<const ushort4*>(src + r * 128 + c4);
  }
}

// One 32x32 output tile: dst = A[100][KD] @ Wt[N][KD]^T + bias.
// GB: B operand is 16B-aligned global. TR: transposed store.
template <int KD, bool TR, bool GB>
__device__ __forceinline__ void tile32(const u16* A, int apitch, const u16* Wt, int wpitch,
                                       const float* __restrict__ bias, u16* dst, int dpitch,
                                       int dbase, int m0, int n0, int l) {
  const int cr = l & 31, g = l >> 5;
  int ar = m0 + cr; if (ar >= Sd) ar = Sd - 1;
  const u16* ap = A + ar * apitch + g * 8;
  const u16* bp = Wt + (n0 + cr) * wpitch + g * 8;
  f32x16 acc = zf16();
#pragma unroll
  for (int k0 = 0; k0 < KD; k0 += 16)
    acc = MFMA32(ld8(ap + k0), GB ? ld8a(bp + k0) : ld8(bp + k0), acc);
  const float bvv = bias[n0 + cr];
#pragma unroll
  for (int i = 0; i < 16; ++i) {
    const int row = m0 + (i & 3) + 8 * (i >> 2) + 4 * g;  // C/D: col=lane&31 (measured)
    if (row < Sd) {
      if (TR) dst[(n0 + cr) * dpitch + dbase + row] = f2bu(acc[i] + bvv);
      else    dst[row * dpitch + dbase + n0 + cr]   = f2bu(acc[i] + bvv);
    }
  }
}

// ---------------------------------------------------------------------------
// Weight preprocessing: f32 global -> bf16 transposed/padded blobs in d_ws.
// ---------------------------------------------------------------------------
__global__ __launch_bounds__(256) void prep_weights(
    const float* __restrict__ Wq, const float* __restrict__ Wk,
    const float* __restrict__ Wqp, const float* __restrict__ Wkp,
    const float* __restrict__ Wv, const float* __restrict__ Wqa,
    const float* __restrict__ Wka, const float* __restrict__ W1,
    const float* __restrict__ Wd, u16* __restrict__ ws) {
  const int t = blockIdx.x * 256 + threadIdx.x;
  const int NT = gridDim.x * 256;
  const float* srcs[5] = {Wq, Wk, Wqp, Wkp, Wv};
#pragma unroll
  for (int wsel = 0; wsel < 5; ++wsel) {
    u16* dst = ws + wsel * 16384;
    const float* src = srcs[wsel];
    for (int i = t; i < 16384; i += NT) {
      const int h = i >> 13, c = (i >> 7) & 63, k = i & 127;
      dst[i] = f2bu(src[k * 128 + h * 64 + c]);
    }
  }
  for (int i = t; i < 16384; i += NT) {
    const int pr = i >> 12, h = (i >> 11) & 1, c = (i >> 6) & 31, k = i & 63;
    const float* src = (pr & 1) ? Wka : Wqa;
    ws[WAT_E + i] = f2bu(src[(pr >> 1) * 4096 + k * 64 + h * 32 + c]);
  }
  for (int i = t; i < 14848; i += NT) {
    const int c = i / W1P, k = i - c * W1P;
    ws[W1T_E + i] = (c < Sd && k < Sd) ? f2bu(W1[k * Sd + c]) : (u16)0;
  }
  for (int i = t; i < 16384; i += NT) {
    const int c = i >> 7, k = i & 127;
    ws[WDT_E + i] = f2bu(Wd[k * 128 + c]);
  }
}

// ---------------------------------------------------------------------------
// PREP mega-kernel: Round-7 structure (LDS weights) + wave-split softmax/V-proj.
// ---------------------------------------------------------------------------
__global__ __launch_bounds__(NTHR) void attn_mega_p(
    const float* __restrict__ input, const float* __restrict__ attrT,
    const float* __restrict__ posE, const float* __restrict__ mask,
    const float* __restrict__ bq, const float* __restrict__ bk,
    const float* __restrict__ bv, const float* __restrict__ bqp,
    const float* __restrict__ bkp, const float* __restrict__ bqa,
    const float* __restrict__ bka, const float* __restrict__ b1,
    const float* __restrict__ W2, const u16* __restrict__ wsw,
    float* __restrict__ ctx) {
  __shared__ __align__(16) char L[LBYTES];
  u16* const ST = (u16*)(L + O_ST);            // [100][420]: [q][st*104+k]
  u16* const QC = (u16*)(L + O_Q);             // [100][196]
  u16* const KC = (u16*)(L + O_K);             // [100][196]
  // staging aliases (in ST arena)
  u16* const SA  = (u16*)(L + O_ST);           // [100][132]
  u16* const SW1 = (u16*)(L + O_ST + 26400);   // [64][132]
  u16* const SW2 = (u16*)(L + O_ST + 43296);   // [64][132]
  u16* const AT0  = (u16*)(L + O_ST);          // [100][68]
  u16* const AT1  = (u16*)(L + O_ST + 13600);
  u16* const WA0Q = (u16*)(L + O_ST + 27200);  // [32][68] x4
  u16* const WA0K = (u16*)(L + O_ST + 31552);
  u16* const WA1Q = (u16*)(L + O_ST + 35904);
  u16* const WA1K = (u16*)(L + O_ST + 40256);
  // gate phase
  u16* const W1T = (u16*)(L + O_K);            // [128][116] incl. pads
  float* const e2s = (float*)(L + O_K + E2S);  // [400] raw gate logits
  // V phase
  u16* const VA  = (u16*)(L + O_Q);            // [100][132] (over dead QC)
  u16* const VT  = (u16*)(L + O_K + 16896);    // [64][116]; ends 31,744 < e2s@32,000

  const int tid = threadIdx.x;
  const int bh = blockIdx.x;
  const int b = bh >> 1, h = bh & 1;
  const size_t row0 = (size_t)b * Sd;
  const int l = tid & 63, w = tid >> 6;
  const int cr = l & 31, g = l >> 5;

  // ---------- S1: input -> SA; Wq/Wk -> LDS; prefetch pos ----------
  stage_rows4<5>(input + row0 * 128, SA, 100, AP, tid, NTHR);
  copy_w64(wsw + WQT_E + h * 8192, SW1, tid, NTHR);
  copy_w64(wsw + WKT_E + h * 8192, SW2, tid, NTHR);
  float4 r2[4];
#pragma unroll
  for (int s = 0; s < 4; ++s) {
    const int fi = tid + s * NTHR;
    if (fi < 3200) r2[s] = ld4(posE + row0 * 128 + fi * 4);
  }
  __syncthreads();

  // ---------- G1: Q/K projections ----------
  {
    const int pr = w >> 3, mt = (w >> 1) & 3, nt = w & 1;
    tile32<128, false, false>(SA, AP, pr ? SW2 : SW1, AP, (pr ? bk : bq) + h * 64,
                              pr ? KC : QC, QKP, 0, mt * 32, nt * 32, l);
  }
  __syncthreads();

  // ---------- S2: pos -> SA; Wqp/Wkp -> LDS; prefetch attr ----------
#pragma unroll
  for (int s = 0; s < 4; ++s) {
    const int fi = tid + s * NTHR;
    if (fi < 3200) {
      ushort4 o;
      o.x = f2bu(r2[s].x); o.y = f2bu(r2[s].y); o.z = f2bu(r2[s].z); o.w = f2bu(r2[s].w);
      *reinterpret_cast<ushort4*>(SA + (fi >> 5) * AP + ((fi & 31) << 2)) = o;
    }
  }
  copy_w64(wsw + WQPT_E + h * 8192, SW1, tid, NTHR);
  copy_w64(wsw + WKPT_E + h * 8192, SW2, tid, NTHR);
  float4 r3[4];
#pragma unroll
  for (int s = 0; s < 4; ++s) {
    const int fi = tid + s * NTHR;
    if (fi < 1600)      r3[s] = ld4(attrT + (size_t)b * 6400 + fi * 4);
    else if (fi < 3200) r3[s] = ld4(attrT + (size_t)(B_ + b) * 6400 + (fi - 1600) * 4);
  }
  __syncthreads();

  // ---------- G2: QP/KP projections ----------
  {
    const int pr = w >> 3, mt = (w >> 1) & 3, nt = w & 1;
    tile32<128, false, false>(SA, AP, pr ? SW2 : SW1, AP, (pr ? bkp : bqp) + h * 64,
                              pr ? KC : QC, QKP, 64, mt * 32, nt * 32, l);
  }
  __syncthreads();

  // ---------- S3: attr -> AT0/AT1; WA -> LDS; prefetch W1T blob ----------
#pragma unroll
  for (int s = 0; s < 4; ++s) {
    const int fi = tid + s * NTHR;
    if (fi < 1600) {
      ushort4 o;
      o.x = f2bu(r3[s].x); o.y = f2bu(r3[s].y); o.z = f2bu(r3[s].z); o.w = f2bu(r3[s].w);
      *reinterpret_cast<ushort4*>(AT0 + (fi >> 4) * ATP + ((fi & 15) << 2)) = o;
    } else if (fi < 3200) {
      const int f3 = fi - 1600;
      ushort4 o;
      o.x = f2bu(r3[s].x); o.y = f2bu(r3[s].y); o.z = f2bu(r3[s].z); o.w = f2bu(r3[s].w);
      *reinterpret_cast<ushort4*>(AT1 + (f3 >> 4) * ATP + ((f3 & 15) << 2)) = o;
    }
  }
  for (int i = tid; i < 2048; i += NTHR) {  // WAT: [4pr][2h][32][64] -> [32][68] x4
    const int pr = i >> 9, row = (i >> 4) & 31, c4 = (i & 15) << 2;
    u16* dst = (pr == 0) ? WA0Q : (pr == 1) ? WA0K : (pr == 2) ? WA1Q : WA1K;
    *reinterpret_cast<ushort4*>(dst + row * ATP + c4) =
        *reinterpret_cast<const ushort4*>(wsw + WAT_E + pr * 4096 + h * 2048 + row * 64 + c4);
  }
  ushort4 rw1[4];  // W1T bf16 blob (3712 ushort4), held through G3+G4
#pragma unroll
  for (int s = 0; s < 4; ++s) {
    const int fi = tid + s * NTHR;
    if (fi < 3712) rw1[s] = reinterpret_cast<const ushort4*>(wsw + W1T_E)[fi];
  }
  __syncthreads();

  // ---------- G3: attribute projections ----------
  {
    const int pr = w >> 2, mt = w & 3;  // 0=A0Q 1=A0K 2=A1Q 3=A1K
    const u16* Asrc = (pr < 2) ? AT0 : AT1;
    const u16* Wt = (pr == 0) ? WA0Q : (pr == 1) ? WA0K : (pr == 2) ? WA1Q : WA1K;
    const float* bs = (pr == 0) ? bqa + h * 32 : (pr == 1) ? bka + h * 32
                     : (pr == 2) ? bqa + 64 + h * 32 : bka + 64 + h * 32;
    tile32<64, false, false>(Asrc, ATP, Wt, ATP, bs, (pr & 1) ? KC : QC, QKP,
                             128 + (pr >> 1) * 32, mt * 32, 0, l);
  }
  __syncthreads();

  // ---------- G4: 4-stream scores -> ST (+ finite row pads 416..419) ----------
  {
    ushort4 z; z.x = z.y = z.z = z.w = 0;
    for (int q = tid; q < Sd; q += NTHR)
      *reinterpret_cast<ushort4*>(ST + q * STP + 416) = z;
  }
  {
    const int mt = w >> 2, nt = w & 3;
    const int m0 = mt * 32, n0 = nt * 32;
    int ar = m0 + cr; if (ar >= Sd) ar = Sd - 1;
    int br = n0 + cr; if (br >= Sd) br = Sd - 1;
    const u16* ap = QC + ar * QKP + g * 8;
    const u16* bp = KC + br * QKP + g * 8;
    f32x16 ai = zf16(), po = zf16(), a0 = zf16(), a1 = zf16();
    ai = MFMA32(ld8(ap + 0),   ld8(bp + 0),   ai);
    ai = MFMA32(ld8(ap + 16),  ld8(bp + 16),  ai);
    ai = MFMA32(ld8(ap + 32),  ld8(bp + 32),  ai);
    ai = MFMA32(ld8(ap + 48),  ld8(bp + 48),  ai);
    po = MFMA32(ld8(ap + 64),  ld8(bp + 64),  po);
    po = MFMA32(ld8(ap + 80),  ld8(bp + 80),  po);
    po = MFMA32(ld8(ap + 96),  ld8(bp + 96),  po);
    po = MFMA32(ld8(ap + 112), ld8(bp + 112), po);
    a0 = MFMA32(ld8(ap + 128), ld8(bp + 128), a0);
    a0 = MFMA32(ld8(ap + 144), ld8(bp + 144), a0);
    a1 = MFMA32(ld8(ap + 160), ld8(bp + 160), a1);
    a1 = MFMA32(ld8(ap + 176), ld8(bp + 176), a1);
    const int col = n0 + cr;
    if (col < STS) {  // writes finite pads at cols 100..103 too
#pragma unroll
      for (int i = 0; i < 16; ++i) {
        const int row = m0 + (i & 3) + 8 * (i >> 2) + 4 * g;
        if (row < Sd) {
          u16* sp = ST + row * STP + col;
          sp[0]       = f2bu(a0[i]);   // attr0
          sp[STS]     = f2bu(a1[i]);   // attr1
          sp[2 * STS] = f2bu(ai[i]);   // item
          sp[3 * STS] = f2bu(po[i]);   // pos
        }
      }
    }
  }
  __syncthreads();

  // ---------- S5: W1T <- rw1 (flat copy); VA <- input (covers G5 A-spill) ----------
#pragma unroll
  for (int s = 0; s < 4; ++s) {
    const int fi = tid + s * NTHR;
    if (fi < 3712) reinterpret_cast<ushort4*>(W1T)[fi] = rw1[s];
  }
  stage_rows4<5>(input + row0 * 128, VA, 100, AP, tid, NTHR);
  __syncthreads();

  // ---------- G5: gate GEMM -> raw logits e2s ----------
  {
    float b1v[4], w2v[4];
#pragma unroll
    for (int nt = 0; nt < 4; ++nt) {
      const int c = nt * 32 + cr;
      b1v[nt] = (c < Sd) ? b1[c] : 0.f;
      w2v[nt] = (c < Sd) ? W2[c] : 0.f;
    }
    for (int mt = w; mt < 13; mt += NW) {
      const int m0 = mt * 32;
      int gr = m0 + cr; if (gr > 399) gr = 399;
      const u16* ap = ST + (gr >> 2) * STP + (gr & 3) * STS + g * 8;
      f32x16 c0 = zf16(), c1 = zf16(), c2 = zf16(), c3 = zf16();
#pragma unroll
      for (int k0 = 0; k0 < 112; k0 += 16) {
        const bf16x8 af = ld8(ap + k0);
        c0 = MFMA32(af, ld8(W1T + (cr)      * W1P + g * 8 + k0), c0);
        c1 = MFMA32(af, ld8(W1T + (32 + cr) * W1P + g * 8 + k0), c1);
        c2 = MFMA32(af, ld8(W1T + (64 + cr) * W1P + g * 8 + k0), c2);
        c3 = MFMA32(af, ld8(W1T + (96 + cr) * W1P + g * 8 + k0), c3);
      }
#pragma unroll
      for (int i = 0; i < 16; ++i) {
        float v = fmaxf(c0[i] + b1v[0], 0.f) * w2v[0]
                + fmaxf(c1[i] + b1v[1], 0.f) * w2v[1]
                + fmaxf(c2[i] + b1v[2], 0.f) * w2v[2]
                + fmaxf(c3[i] + b1v[3], 0.f) * w2v[3];
#pragma unroll
        for (int mm = 1; mm < 32; mm <<= 1) v += __shfl_xor(v, mm);
        if (cr == 0) {
          const int go = m0 + (i & 3) + 8 * (i >> 2) + 4 * g;
          if (go < 400) e2s[go] = v;
        }
      }
    }
  }
  __syncthreads();

  // ---------- SPLIT: waves 0-7 softmax || waves 8-15 V-proj (global B-frags) ----------
  if (w < 8) {
    for (int q = w; q < Sd; q += 8) {
      const float* ez = e2s + q * 4;
      float e0 = ez[0], e1 = ez[1], e2v = ez[2], e3 = ez[3];
      const float mg = fmaxf(fmaxf(e0, e1), fmaxf(e2v, e3));
      e0 = __expf(e0 - mg); e1 = __expf(e1 - mg);
      e2v = __expf(e2v - mg); e3 = __expf(e3 - mg);
      const float ginv = 1.0f / (e0 + e1 + e2v + e3);
      const float g0v = e0 * ginv, g1v = e1 * ginv, g2v = e2v * ginv, g3v = e3 * ginv;
      u16* const sp = ST + q * STP;
      const float* const mp = mask + (size_t)b * 10000 + q * 100;
      float x1 = g0v * bfr(sp[l]) + g1v * bfr(sp[STS + l]) +
                 g2v * bfr(sp[2 * STS + l]) + g3v * bfr(sp[3 * STS + l]);
      x1 = x1 * 0.125f + mp[l];
      const bool v2 = (l < 36);
      float x2 = -3e38f;
      if (v2) {
        const int k2 = 64 + l;
        x2 = g0v * bfr(sp[k2]) + g1v * bfr(sp[STS + k2]) +
             g2v * bfr(sp[2 * STS + k2]) + g3v * bfr(sp[3 * STS + k2]);
        x2 = x2 * 0.125f + mp[k2];
      }
      const float M = wmax(fmaxf(x1, x2));
      const float ea = __expf(x1 - M);
      const float eb = v2 ? __expf(x2 - M) : 0.f;
      const float inv = 1.0f / wsum(ea + eb);
      sp[l] = f2bu(ea * inv);
      if (v2) sp[64 + l] = f2bu(eb * inv);
    }
  } else {
    const int u = w - 8;
    const int mt = u >> 1, nt = u & 1;
    if (mt == 3 && g == 0) {  // zero pad cols 100..111 of this nt's VT rows
      ushort4 z; z.x = z.y = z.z = z.w = 0;
      u16* vp = VT + (nt * 32 + cr) * VTP + 100;
      *reinterpret_cast<ushort4*>(vp)     = z;
      *reinterpret_cast<ushort4*>(vp + 4) = z;
      *reinterpret_cast<ushort4*>(vp + 8) = z;
    }
    tile32<128, true, true>(VA, AP, wsw + WVT_E + h * 8192, 128, bv + h * 64,
                            VT, VTP, 0, mt * 32, nt * 32, l);
  }
  __syncthreads();

  // ---------- G8: PV -> ctx (global f32) ----------
  if (w < 8) {
    const int mt = w >> 1, nt = w & 1;
    const int m0 = mt * 32, n0 = nt * 32;
    int ar = m0 + cr; if (ar >= Sd) ar = Sd - 1;
    const u16* ap = ST + ar * STP + g * 8;
    const u16* bp = VT + (n0 + cr) * VTP + g * 8;
    f32x16 acc = zf16();
#pragma unroll
    for (int k0 = 0; k0 < 112; k0 += 16)
      acc = MFMA32(ld8(ap + k0), ld8(bp + k0), acc);
#pragma unroll
    for (int i = 0; i < 16; ++i) {
      const int row = m0 + (i & 3) + 8 * (i >> 2) + 4 * g;
      if (row < Sd)
        ctx[(row0 + row) * 128 + h * 64 + n0 + cr] = acc[i];
    }
  }
}

// ---------------------------------------------------------------------------
// Output dense (32x32 MFMA) + bias + residual + LayerNorm, in place over d_out.
// 512 threads, 128 rows/block, bf16 Hs.
// ---------------------------------------------------------------------------
template <bool PREP>
__global__ __launch_bounds__(512) void dense_ln(
    const float* __restrict__ ctxg, const float* __restrict__ Wd,
    const float* __restrict__ bd, const float* __restrict__ resid,
    const float* __restrict__ lng, const float* __restrict__ lnb,
    const u16* __restrict__ wsw, float* __restrict__ out) {
  __shared__ __align__(16) char L[101376];
  u16* const Ab  = (u16*)L;              // [128][132]
  u16* const WdT = (u16*)(L + 33792);    // [128][132]
  u16* const Hs  = (u16*)(L + 67584);    // [128][132] bf16 (GEMM term only)
  const int tid = threadIdx.x;
  const size_t row0 = (size_t)blockIdx.x * 128;
  const int l = tid & 63, w = tid >> 6, cr = l & 31, g = l >> 5;

  stage_rows4<5>(ctxg + row0 * 128, Ab, 128, AP, tid, 512);
  if constexpr (PREP) {
    for (int i = tid; i < 4096; i += 512) {
      const int r = i >> 5, c4 = (i & 31) << 2;
      *reinterpret_cast<ushort4*>(WdT + r * AP + c4) =
          *reinterpret_cast<const ushort4*>(wsw + WDT_E + r * 128 + c4);
    }
  } else {
    stage_wt<7>(Wd, 128, 0, WdT, 128, AP, tid, 512);
  }
  __syncthreads();

  for (int u = w; u < 16; u += 8) {
    const int m0 = (u >> 2) * 32, n0 = (u & 3) * 32;
    const u16* ap = Ab + (m0 + cr) * AP + g * 8;
    const u16* bp = WdT + (n0 + cr) * AP + g * 8;
    f32x16 acc = zf16();
#pragma unroll
    for (int k0 = 0; k0 < 128; k0 += 16)
      acc = MFMA32(ld8(ap + k0), ld8(bp + k0), acc);
#pragma unroll
    for (int i = 0; i < 16; ++i) {
      const int row = m0 + (i & 3) + 8 * (i >> 2) + 4 * g;
      Hs[row * AP + n0 + cr] = f2bu(acc[i]);
    }
  }
  __syncthreads();

  for (int rr = w; rr < 128; rr += 8) {
    const size_t grow = row0 + rr;
    const float h1 = bfr(Hs[rr * AP + l])      + bd[l]      + resid[grow * 128 + l];
    const float h2 = bfr(Hs[rr * AP + 64 + l]) + bd[64 + l] + resid[grow * 128 + 64 + l];
    const float mu = wsum(h1 + h2) * (1.0f / 128.0f);
    const float d1 = h1 - mu, d2 = h2 - mu;
    const float var = wsum(d1 * d1 + d2 * d2) * (1.0f / 128.0f);
    const float rs = rsqrtf(var + 1e-12f);
    out[grow * 128 + l]      = d1 * rs * lng[l]      + lnb[l];
    out[grow * 128 + 64 + l] = d2 * rs * lng[64 + l] + lnb[64 + l];
  }
}

// ---------------------------------------------------------------------------
// Fallback mega-kernel (Round-6/7 structure, no d_ws).
// ---------------------------------------------------------------------------
__global__ __launch_bounds__(NTHR) void attn_mega_fb(
    const float* __restrict__ input, const float* __restrict__ attrT,
    const float* __restrict__ posE, const float* __restrict__ mask,
    const float* __restrict__ Wq, const float* __restrict__ bq,
    const float* __restrict__ Wk, const float* __restrict__ bk,
    const float* __restrict__ Wv, const float* __restrict__ bv,
    const float* __restrict__ Wqp, const float* __restrict__ bqp,
    const float* __restrict__ Wkp, const float* __restrict__ bkp,
    const float* __restrict__ Wqa, const float* __restrict__ bqa,
    const float* __restrict__ Wka, const float* __restrict__ bka,
    const float* __restrict__ W1, const float* __restrict__ b1,
    const float* __restrict__ W2, float* __restrict__ ctx) {
  __shared__ __align__(16) char L[LBYTES];
  u16* const ST = (u16*)(L + O_ST);
  u16* const QC = (u16*)(L + O_Q);
  u16* const KC = (u16*)(L + O_K);
  u16* const SA  = (u16*)(L + O_ST);
  u16* const SW1 = (u16*)(L + O_ST + 26400);
  u16* const SW2 = (u16*)(L + O_ST + 43296);
  u16* const AT0  = (u16*)(L + O_ST);
  u16* const AT1  = (u16*)(L + O_ST + 13600);
  u16* const WA0Q = (u16*)(L + O_ST + 27200);
  u16* const WA0K = (u16*)(L + O_ST + 31552);
  u16* const WA1Q = (u16*)(L + O_ST + 35904);
  u16* const WA1K = (u16*)(L + O_ST + 40256);
  u16* const W1T = (u16*)(L + O_K);
  float* const e2s = (float*)(L + O_K + E2S);
  u16* const VA  = (u16*)(L + O_Q);
  u16* const WVT = (u16*)(L + O_K);
  u16* const VT  = (u16*)(L + O_K + 16896);

  const int tid = threadIdx.x;
  const int bh = blockIdx.x;
  const int b = bh >> 1, h = bh & 1;
  const size_t row0 = (size_t)b * Sd;
  const int l = tid & 63, w = tid >> 6;
  const int cr = l & 31, g = l >> 5;

  stage_rows4<5>(input + row0 * 128, SA, 100, AP, tid, NTHR);
  stage_wt6(Wq, h * 64, SW1, tid, NTHR);
  stage_wt6(Wk, h * 64, SW2, tid, NTHR);
  float4 r2[8];
#pragma unroll
  for (int s = 0; s < 8; ++s) {
    const int fi = tid + s * NTHR;
    if (fi < 3200) r2[s] = ld4(posE + row0 * 128 + fi * 4);
    else if (fi < 5248) {
      const int f2 = fi - 3200, k = f2 >> 4, c0 = (f2 & 15) << 2;
      r2[s] = ld4(Wqp + k * 128 + h * 64 + c0);
    } else if (fi < 7296) {
      const int f2 = fi - 5248, k = f2 >> 4, c0 = (f2 & 15) << 2;
      r2[s] = ld4(Wkp + k * 128 + h * 64 + c0);
    }
  }
  __syncthreads();
  {
    const int pr = w >> 3, mt = (w >> 1) & 3, nt = w & 1;
    tile32<128, false, false>(SA, AP, pr ? SW2 : SW1, AP, (pr ? bk : bq) + h * 64,
                              pr ? KC : QC, QKP, 0, mt * 32, nt * 32, l);
  }
  __syncthreads();
#pragma unroll
  for (int s = 0; s < 8; ++s) {
    const int fi = tid + s * NTHR;
    if (fi < 3200) {
      ushort4 o;
      o.x = f2bu(r2[s].x); o.y = f2bu(r2[s].y); o.z = f2bu(r2[s].z); o.w = f2bu(r2[s].w);
      *reinterpret_cast<ushort4*>(SA + (fi >> 5) * AP + ((fi & 31) << 2)) = o;
    } else if (fi < 5248) {
      const int f2 = fi - 3200, k = f2 >> 4, c0 = (f2 & 15) << 2;
      SW1[c0 * AP + k] = f2bu(r2[s].x); SW1[(c0 + 1) * AP + k] = f2bu(r2[s].y);
      SW1[(c0 + 2) * AP + k] = f2bu(r2[s].z); SW1[(c0 + 3) * AP + k] = f2bu(r2[s].w);
    } else if (fi < 7296) {
      const int f2 = fi - 5248, k = f2 >> 4, c0 = (f2 & 15) << 2;
      SW2[c0 * AP + k] = f2bu(r2[s].x); SW2[(c0 + 1) * AP + k] = f2bu(r2[s].y);
      SW2[(c0 + 2) * AP + k] = f2bu(r2[s].z); SW2[(c0 + 3) * AP + k] = f2bu(r2[s].w);
    }
  }
  float4 r3[6];
#pragma unroll
  for (int s = 0; s < 6; ++s) {
    const int fi = tid + s * NTHR;
    if (fi < 1600) r3[s] = ld4(attrT + (size_t)b * 6400 + fi * 4);
    else if (fi < 3200) r3[s] = ld4(attrT + (size_t)(B_ + b) * 6400 + (fi - 1600) * 4);
    else if (fi < 5248) {
      const int f3 = fi - 3200, which = f3 >> 9, fj = f3 & 511;
      const int k = fj >> 3, c0 = (fj & 7) << 2;
      const float* src = (which == 0) ? Wqa : (which == 1) ? Wka
                       : (which == 2) ? (Wqa + 4096) : (Wka + 4096);
      r3[s] = ld4(src + k * 64 + h * 32 + c0);
    }
  }
  __syncthreads();
  {
    const int pr = w >> 3, mt = (w >> 1) & 3, nt = w & 1;
    tile32<128, false, false>(SA, AP, pr ? SW2 : SW1, AP, (pr ? bkp : bqp) + h * 64,
                              pr ? KC : QC, QKP, 64, mt * 32, nt * 32, l);
  }
  __syncthreads();
#pragma unroll
  for (int s = 0; s < 6; ++s) {
    const int fi = tid + s * NTHR;
    if (fi < 1600) {
      ushort4 o;
      o.x = f2bu(r3[s].x); o.y = f2bu(r3[s].y); o.z = f2bu(r3[s].z); o.w = f2bu(r3[s].w);
      *reinterpret_cast<ushort4*>(AT0 + (fi >> 4) * ATP + ((fi & 15) << 2)) = o;
    } else if (fi < 3200) {
      const int f3 = fi - 1600;
      ushort4 o;
      o.x = f2bu(r3[s].x); o.y = f2bu(r3[s].y); o.z = f2bu(r3[s].z); o.w = f2bu(r3[s].w);
      *reinterpret_cast<ushort4*>(AT1 + (f3 >> 4) * ATP + ((f3 & 15) << 2)) = o;
    } else if (fi < 5248) {
      const int f3 = fi - 3200, which = f3 >> 9, fj = f3 & 511;
      const int k = fj >> 3, c0 = (fj & 7) << 2;
      u16* dst = (which == 0) ? WA0Q : (which == 1) ? WA0K
               : (which == 2) ? WA1Q : WA1K;
      dst[c0 * ATP + k] = f2bu(r3[s].x); dst[(c0 + 1) * ATP + k] = f2bu(r3[s].y);
      dst[(c0 + 2) * ATP + k] = f2bu(r3[s].z); dst[(c0 + 3) * ATP + k] = f2bu(r3[s].w);
    }
  }
  float4 r5[3];
#pragma unroll
  for (int s = 0; s < 3; ++s) {
    const int fi = tid + s * NTHR;
    if (fi < 2500) r5[s] = ld4(W1 + fi * 4);
  }
  __syncthreads();
  {
    const int pr = w >> 2, mt = w & 3;
    const u16* Asrc = (pr < 2) ? AT0 : AT1;
    const u16* Wt = (pr == 0) ? WA0Q : (pr == 1) ? WA0K : (pr == 2) ? WA1Q : WA1K;
    const float* bs = (pr == 0) ? bqa + h * 32 : (pr == 1) ? bka + h * 32
                     : (pr == 2) ? bqa + 64 + h * 32 : bka + 64 + h * 32;
    tile32<64, false, false>(Asrc, ATP, Wt, ATP, bs, (pr & 1) ? KC : QC, QKP,
                             128 + (pr >> 1) * 32, mt * 32, 0, l);
  }
  __syncthreads();
  {
    ushort4 z; z.x = z.y = z.z = z.w = 0;
    for (int q = tid; q < Sd; q += NTHR)
      *reinterpret_cast<ushort4*>(ST + q * STP + 416) = z;
  }
  {
    const int mt = w >> 2, nt = w & 3;
    const int m0 = mt * 32, n0 = nt * 32;
    int ar = m0 + cr; if (ar >= Sd) ar = Sd - 1;
    int br = n0 + cr; if (br >= Sd) br = Sd - 1;
    const u16* ap = QC + ar * QKP + g * 8;
    const u16* bp = KC + br * QKP + g * 8;
    f32x16 ai = zf16(), po = zf16(), a0 = zf16(), a1 = zf16();
    ai = MFMA32(ld8(ap + 0),   ld8(bp + 0),   ai);
    ai = MFMA32(ld8(ap + 16),  ld8(bp + 16),  ai);
    ai = MFMA32(ld8(ap + 32),  ld8(bp + 32),  ai);
    ai = MFMA32(ld8(ap + 48),  ld8(bp + 48),  ai);
    po = MFMA32(ld8(ap + 64),  ld8(bp + 64),  po);
    po = MFMA32(ld8(ap + 80),  ld8(bp + 80),  po);
    po = MFMA32(ld8(ap + 96),  ld8(bp + 96),  po);
    po = MFMA32(ld8(ap + 112), ld8(bp + 112), po);
    a0 = MFMA32(ld8(ap + 128), ld8(bp + 128), a0);
    a0 = MFMA32(ld8(ap + 144), ld8(bp + 144), a0);
    a1 = MFMA32(ld8(ap + 160), ld8(bp + 160), a1);
    a1 = MFMA32(ld8(ap + 176), ld8(bp + 176), a1);
    const int col = n0 + cr;
    if (col < STS) {
#pragma unroll
      for (int i = 0; i < 16; ++i) {
        const int row = m0 + (i & 3) + 8 * (i >> 2) + 4 * g;
        if (row < Sd) {
          u16* sp = ST + row * STP + col;
          sp[0]       = f2bu(a0[i]);
          sp[STS]     = f2bu(a1[i]);
          sp[2 * STS] = f2bu(ai[i]);
          sp[3 * STS] = f2bu(po[i]);
        }
      }
    }
  }
  __syncthreads();
  {
    ushort4 z; z.x = z.y = z.z = z.w = 0;
    if (tid < 812)
      *reinterpret_cast<ushort4*>(W1T + 11600 + tid * 4) = z;
    if (tid < 400) {
      const int c = tid >> 2, kq = 100 + ((tid & 3) << 2);
      *reinterpret_cast<ushort4*>(W1T + c * W1P + kq) = z;
    }
  }
  if (tid < 8) ((u16*)(L + O_Q))[tid] = 0;
#pragma unroll
  for (int s = 0; s < 3; ++s) {
    const int fi = tid + s * NTHR;
    if (fi < 2500) {
#pragma unroll
      for (int j = 0; j < 4; ++j) {
        const int o = fi * 4 + j;
        const int k = o / 100, c = o - k * 100;
        W1T[c * W1P + k] = f2bu((j == 0) ? r5[s].x : (j == 1) ? r5[s].y
                                : (j == 2) ? r5[s].z : r5[s].w);
      }
    }
  }
  __syncthreads();
  {
    float b1v[4], w2v[4];
#pragma unroll
    for (int nt = 0; nt < 4; ++nt) {
      const int c = nt * 32 + cr;
      b1v[nt] = (c < Sd) ? b1[c] : 0.f;
      w2v[nt] = (c < Sd) ? W2[c] : 0.f;
    }
    for (int mt = w; mt < 13; mt += NW) {
      const int m0 = mt * 32;
      int gr = m0 + cr; if (gr > 399) gr = 399;
      const u16* ap = ST + (gr >> 2) * STP + (gr & 3) * STS + g * 8;
      f32x16 c0 = zf16(), c1 = zf16(), c2 = zf16(), c3 = zf16();
#pragma unroll
      for (int k0 = 0; k0 < 112; k0 += 16) {
        const bf16x8 af = ld8(ap + k0);
        c0 = MFMA32(af, ld8(W1T + (cr)      * W1P + g * 8 + k0), c0);
        c1 = MFMA32(af, ld8(W1T + (32 + cr) * W1P + g * 8 + k0), c1);
        c2 = MFMA32(af, ld8(W1T + (64 + cr) * W1P + g * 8 + k0), c2);
        c3 = MFMA32(af, ld8(W1T + (96 + cr) * W1P + g * 8 + k0), c3);
      }
#pragma unroll
      for (int i = 0; i < 16; ++i) {
        float v = fmaxf(c0[i] + b1v[0], 0.f) * w2v[0]
                + fmaxf(c1[i] + b1v[1], 0.f) * w2v[1]
                + fmaxf(c2[i] + b1v[2], 0.f) * w2v[2]
                + fmaxf(c3[i] + b1v[3], 0.f) * w2v[3];
#pragma unroll
        for (int mm = 1; mm < 32; mm <<= 1) v += __shfl_xor(v, mm);
        if (cr == 0) {
          const int go = m0 + (i & 3) + 8 * (i >> 2) + 4 * g;
          if (go < 400) e2s[go] = v;
        }
      }
    }
  }
  __syncthreads();
  stage_rows4<5>(input + row0 * 128, VA, 100, AP, tid, NTHR);
  stage_wt6(Wv, h * 64, WVT, tid, NTHR);
  {
    ushort4 z; z.x = z.y = z.z = z.w = 0;
    for (int i2 = tid; i2 < 64 * VTP / 4; i2 += NTHR)
      *reinterpret_cast<ushort4*>(VT + i2 * 4) = z;
  }
  for (int q = w; q < Sd; q += NW) {
    const float* ez = e2s + q * 4;
    float e0 = ez[0], e1 = ez[1], e2v = ez[2], e3 = ez[3];
    const float mg = fmaxf(fmaxf(e0, e1), fmaxf(e2v, e3));
    e0 = __expf(e0 - mg); e1 = __expf(e1 - mg);
    e2v = __expf(e2v - mg); e3 = __expf(e3 - mg);
    const float ginv = 1.0f / (e0 + e1 + e2v + e3);
    const float g0v = e0 * ginv, g1v = e1 * ginv, g2v = e2v * ginv, g3v = e3 * ginv;
    u16* const sp = ST + q * STP;
    const float* const mp = mask + (size_t)b * 10000 + q * 100;
    float x1 = g0v * bfr(sp[l]) + g1v * bfr(sp[STS + l]) +
               g2v * bfr(sp[2 * STS + l]) + g3v * bfr(sp[3 * STS + l]);
    x1 = x1 * 0.125f + mp[l];
    const bool v2 = (l < 36);
    float x2 = -3e38f;
    if (v2) {
      const int k2 = 64 + l;
      x2 = g0v * bfr(sp[k2]) + g1v * bfr(sp[STS + k2]) +
           g2v * bfr(sp[2 * STS + k2]) + g3v * bfr(sp[3 * STS + k2]);
      x2 = x2 * 0.125f + mp[k2];
    }
    const float M = wmax(fmaxf(x1, x2));
    const float ea = __expf(x1 - M);
    const float eb = v2 ? __expf(x2 - M) : 0.f;
    const float inv = 1.0f / wsum(ea + eb);
    sp[l] = f2bu(ea * inv);
    if (v2) sp[64 + l] = f2bu(eb * inv);
  }
  __syncthreads();
  if (w < 8) {
    const int mt = w >> 1, nt = w & 1;
    tile32<128, true, false>(VA, AP, WVT, AP, bv + h * 64, VT, VTP, 0, mt * 32, nt * 32, l);
  }
  __syncthreads();
  if (w < 8) {
    const int mt = w >> 1, nt = w & 1;
    const int m0 = mt * 32, n0 = nt * 32;
    int ar = m0 + cr; if (ar >= Sd) ar = Sd - 1;
    const u16* ap = ST + ar * STP + g * 8;
    const u16* bp = VT + (n0 + cr) * VTP + g * 8;
    f32x16 acc = zf16();
#pragma unroll
    for (int k0 = 0; k0 < 112; k0 += 16)
      acc = MFMA32(ld8(ap + k0), ld8(bp + k0), acc);
#pragma unroll
    for (int i = 0; i < 16; ++i) {
      const int row = m0 + (i & 3) + 8 * (i >> 2) + 4 * g;
      if (row < Sd)
        ctx[(row0 + row) * 128 + h * 64 + n0 + cr] = acc[i];
    }
  }
}

}  // namespace

extern "C" void kernel_launch(void* const* d_in, const int* in_sizes, int n_in,
                              void* d_out, int out_size, void* d_ws,
                              size_t ws_size, hipStream_t stream) {
  (void)in_sizes; (void)n_in; (void)out_size;

  const float* input = (const float*)d_in[0];
  const float* attrT = (const float*)d_in[1];
  const float* posE  = (const float*)d_in[2];
  const float* mask  = (const float*)d_in[3];
  const float* Wq  = (const float*)d_in[4];  const float* bq  = (const float*)d_in[5];
  const float* Wk  = (const float*)d_in[6];  const float* bk  = (const float*)d_in[7];
  const float* Wv  = (const float*)d_in[8];  const float* bv  = (const float*)d_in[9];
  const float* Wqp = (const float*)d_in[10]; const float* bqp = (const float*)d_in[11];
  const float* Wkp = (const float*)d_in[12]; const float* bkp = (const float*)d_in[13];
  const float* Wqa = (const float*)d_in[14]; const float* bqa = (const float*)d_in[15];
  const float* Wka = (const float*)d_in[16]; const float* bka = (const float*)d_in[17];
  const float* W1  = (const float*)d_in[18]; const float* b1  = (const float*)d_in[19];
  const float* W2  = (const float*)d_in[20];
  const float* Wd  = (const float*)d_in[22]; const float* bd  = (const float*)d_in[23];
  const float* lng = (const float*)d_in[24]; const float* lnb = (const float*)d_in[25];

  float* ctx = (float*)d_out;  // d_out doubles as ctx staging, then final output

  if (ws_size >= WS_NEED) {
    u16* wsw = (u16*)d_ws;
    prep_weights<<<dim3(128), dim3(256), 0, stream>>>(
        Wq, Wk, Wqp, Wkp, Wv, Wqa, Wka, W1, Wd, wsw);
    attn_mega_p<<<dim3(B_ * 2), dim3(NTHR), 0, stream>>>(
        input, attrT, posE, mask, bq, bk, bv, bqp, bkp, bqa, bka, b1, W2, wsw, ctx);
    dense_ln<true><<<dim3(BS_ / 128), dim3(512), 0, stream>>>(
        ctx, Wd, bd, input, lng, lnb, wsw, ctx);
  } else {
    attn_mega_fb<<<dim3(B_ * 2), dim3(NTHR), 0, stream>>>(
        input, attrT, posE, mask, Wq, bq, Wk, bk, Wv, bv, Wqp, bqp, Wkp, bkp,
        Wqa, bqa, Wka, bka, W1, b1, W2, ctx);
    dense_ln<false><<<dim3(BS_ / 128), dim3(512), 0, stream>>>(
        ctx, Wd, bd, input, lng, lnb, nullptr, ctx);
  }
}

// Round 10
// 355.265 us; speedup vs baseline: 1.1177x; 1.0121x over previous
//
#include <hip/hip_runtime.h>
#include <hip/hip_bf16.h>

using bf16 = __hip_bfloat16;
using u16 = unsigned short;
typedef __attribute__((ext_vector_type(8))) short bf16x8;
typedef __attribute__((ext_vector_type(16))) float f32x16;

namespace {

constexpr int B_  = 1024;
constexpr int Sd  = 100;
constexpr int BS_ = B_ * Sd;

constexpr int NTHR = 1024;   // 16 waves -> 4 waves/SIMD
constexpr int NW   = 16;

constexpr int STP = 420;   // ST q-row pitch; 2-way bank alias (free)
constexpr int STS = 104;   // per-stream pitch inside a q-row
constexpr int QKP = 196;   // QC/KC pitch
constexpr int AP  = 132;   // 128-wide staging pitch
constexpr int ATP = 68;    // 64-wide attr staging pitch
constexpr int W1P = 116;   // W1T pitch (112 would be 8-way conflict)
constexpr int VTP = 116;

constexpr int O_ST = 0;        // ST [100][420] = 84,000 B (P1-P3: staging scratch)
constexpr int O_Q  = 84000;    // QC [100][196] = 39,200 (P6+: VA [100][132])
constexpr int O_K  = 123200;   // KC [100][196] = 39,200 (G5: W1T+e2s; P6+: WVT, VT, e2s)
constexpr int E2S  = 32000;    // e2s f32[400] at O_K+32000 (dead-KC tail; > VT end 31744)
constexpr int LBYTES = 162400;

// d_ws bf16 blob element offsets (prep_weights layout)
constexpr int WQT_E  = 0;        // [2h][64c][128k]
constexpr int WKT_E  = 16384;
constexpr int WQPT_E = 32768;
constexpr int WKPT_E = 49152;
constexpr int WVT_E  = 65536;
constexpr int WAT_E  = 81920;    // [4pr][2h][32c][64k]
constexpr int W1T_E  = 98304;    // [128c][116k] incl. zero pads
constexpr int WDT_E  = 113152;   // [128c][128k]
constexpr size_t WS_NEED = 129536ull * 2;  // 259,072 B

__device__ __forceinline__ float bfr(u16 u) {
  unsigned int x = ((unsigned int)u) << 16;
  float f; __builtin_memcpy(&f, &x, 4); return f;
}
__device__ __forceinline__ u16 f2bu(float x) {
  bf16 h = __float2bfloat16(x);
  u16 u; __builtin_memcpy(&u, &h, 2); return u;
}
__device__ __forceinline__ float4 ld4(const float* p) {
  return *reinterpret_cast<const float4*>(p);
}
__device__ __forceinline__ float wsum(float v) {
#pragma unroll
  for (int m = 32; m > 0; m >>= 1) v += __shfl_xor(v, m);
  return v;
}
__device__ __forceinline__ float wmax(float v) {
#pragma unroll
  for (int m = 32; m > 0; m >>= 1) v = fmaxf(v, __shfl_xor(v, m));
  return v;
}
__device__ __forceinline__ f32x16 zf16() {
  f32x16 z;
#pragma unroll
  for (int i = 0; i < 16; ++i) z[i] = 0.f;
  return z;
}
__device__ __forceinline__ f32x16 MFMA32(bf16x8 a, bf16x8 b, f32x16 c) {
  return __builtin_amdgcn_mfma_f32_32x32x16_bf16(a, b, c, 0, 0, 0);
}

// 8 contiguous bf16, 8B-aligned (LDS): two b64 reads. Same helper for A and B
// operands -> any k-permutation inside the 16-block cancels in the MFMA.
__device__ __forceinline__ bf16x8 ld8(const u16* p) {
  const ushort4 a = *reinterpret_cast<const ushort4*>(p);
  const ushort4 b = *reinterpret_cast<const ushort4*>(p + 4);
  bf16x8 f;
  f[0] = (short)a.x; f[1] = (short)a.y; f[2] = (short)a.z; f[3] = (short)a.w;
  f[4] = (short)b.x; f[5] = (short)b.y; f[6] = (short)b.z; f[7] = (short)b.w;
  return f;
}

// global f32 rows (contiguous, ncol = 4<<L4) -> LDS bf16 [nrow][pitch]
template <int L4>
__device__ __forceinline__ void stage_rows4(const float* __restrict__ src, u16* dst,
                                            int nrow, int pitch, int tid, int nthr) {
  for (int i = tid; i < (nrow << L4); i += nthr) {
    const int rr = i >> L4, cc = (i & ((1 << L4) - 1)) << 2;
    const float4 v = *reinterpret_cast<const float4*>(src + ((size_t)rr << (L4 + 2)) + cc);
    ushort4 o;
    o.x = f2bu(v.x); o.y = f2bu(v.y); o.z = f2bu(v.z); o.w = f2bu(v.w);
    *reinterpret_cast<ushort4*>(dst + rr * pitch + cc) = o;
  }
}
// W[k][coff+c] -> WT[c][k] bf16 (fallback path only)
template <int LC>
__device__ __forceinline__ void stage_wt(const float* __restrict__ W, int ldw, int coff,
                                         u16* dst, int kd, int pitch, int tid, int nthr) {
  constexpr int NC = 1 << LC;
  for (int idx = tid; idx < NC * kd; idx += nthr) {
    const int k = idx >> LC, c = idx & (NC - 1);
    dst[c * pitch + k] = f2bu(W[k * ldw + coff + c]);
  }
}
__device__ __forceinline__ void stage_wt6(const float* __restrict__ W, int coff,
                                          u16* dst, int tid, int nthr) {
  stage_wt<6>(W, 128, coff, dst, 128, AP, tid, nthr);
}
// ws bf16 [64][128] blob -> LDS [64][AP] (vectorized copy)
__device__ __forceinline__ void copy_w64(const u16* __restrict__ src, u16* dst,
                                         int tid, int nthr) {
  for (int i = tid; i < 2048; i += nthr) {
    const int r = i >> 5, c4 = (i & 31) << 2;
    *reinterpret_cast<ushort4*>(dst + r * AP + c4) =
        *reinterpret_cast<const ushort4*>(src + r * 128 + c4);
  }
}

// One 32x32 output tile: dst = A[100][KD] @ Wt[N][KD]^T + bias.
// TR=false: dst[row][dbase+n0+col]; TR=true: dst[n0+col][dbase+row].
template <int KD, bool TR>
__device__ __forceinline__ void tile32(const u16* A, int apitch, const u16* Wt, int wpitch,
                                       const float* __restrict__ bias, u16* dst, int dpitch,
                                       int dbase, int m0, int n0, int l) {
  const int cr = l & 31, g = l >> 5;
  int ar = m0 + cr; if (ar >= Sd) ar = Sd - 1;
  const u16* ap = A + ar * apitch + g * 8;
  const u16* bp = Wt + (n0 + cr) * wpitch + g * 8;
  f32x16 acc = zf16();
#pragma unroll
  for (int k0 = 0; k0 < KD; k0 += 16)
    acc = MFMA32(ld8(ap + k0), ld8(bp + k0), acc);
  const float bvv = bias[n0 + cr];
#pragma unroll
  for (int i = 0; i < 16; ++i) {
    const int row = m0 + (i & 3) + 8 * (i >> 2) + 4 * g;  // C/D: col=lane&31 (measured)
    if (row < Sd) {
      if (TR) dst[(n0 + cr) * dpitch + dbase + row] = f2bu(acc[i] + bvv);
      else    dst[row * dpitch + dbase + n0 + cr]   = f2bu(acc[i] + bvv);
    }
  }
}

// ---------------------------------------------------------------------------
// Weight preprocessing: f32 global -> bf16 transposed/padded blobs in d_ws.
// ---------------------------------------------------------------------------
__global__ __launch_bounds__(256) void prep_weights(
    const float* __restrict__ Wq, const float* __restrict__ Wk,
    const float* __restrict__ Wqp, const float* __restrict__ Wkp,
    const float* __restrict__ Wv, const float* __restrict__ Wqa,
    const float* __restrict__ Wka, const float* __restrict__ W1,
    const float* __restrict__ Wd, u16* __restrict__ ws) {
  const int t = blockIdx.x * 256 + threadIdx.x;
  const int NT = gridDim.x * 256;
  const float* srcs[5] = {Wq, Wk, Wqp, Wkp, Wv};
#pragma unroll
  for (int wsel = 0; wsel < 5; ++wsel) {
    u16* dst = ws + wsel * 16384;
    const float* src = srcs[wsel];
    for (int i = t; i < 16384; i += NT) {
      const int h = i >> 13, c = (i >> 7) & 63, k = i & 127;
      dst[i] = f2bu(src[k * 128 + h * 64 + c]);
    }
  }
  for (int i = t; i < 16384; i += NT) {
    const int pr = i >> 12, h = (i >> 11) & 1, c = (i >> 6) & 31, k = i & 63;
    const float* src = (pr & 1) ? Wka : Wqa;
    ws[WAT_E + i] = f2bu(src[(pr >> 1) * 4096 + k * 64 + h * 32 + c]);
  }
  for (int i = t; i < 14848; i += NT) {
    const int c = i / W1P, k = i - c * W1P;
    ws[W1T_E + i] = (c < Sd && k < Sd) ? f2bu(W1[k * Sd + c]) : (u16)0;
  }
  for (int i = t; i < 16384; i += NT) {
    const int c = i >> 7, k = i & 127;
    ws[WDT_E + i] = f2bu(Wd[k * 128 + c]);
  }
}

// ---------------------------------------------------------------------------
// Mega-kernel: Round-7 structure; P6 wave-split (staging || softmax), all-LDS.
// PREP=true: weights pre-converted/transposed in d_ws.
// ---------------------------------------------------------------------------
template <bool PREP>
__global__ __launch_bounds__(NTHR) void attn_mega(
    const float* __restrict__ input, const float* __restrict__ attrT,
    const float* __restrict__ posE, const float* __restrict__ mask,
    const float* __restrict__ Wq, const float* __restrict__ bq,
    const float* __restrict__ Wk, const float* __restrict__ bk,
    const float* __restrict__ Wv, const float* __restrict__ bv,
    const float* __restrict__ Wqp, const float* __restrict__ bqp,
    const float* __restrict__ Wkp, const float* __restrict__ bkp,
    const float* __restrict__ Wqa, const float* __restrict__ bqa,
    const float* __restrict__ Wka, const float* __restrict__ bka,
    const float* __restrict__ W1, const float* __restrict__ b1,
    const float* __restrict__ W2, const u16* __restrict__ wsw,
    float* __restrict__ ctx) {
  __shared__ __align__(16) char L[LBYTES];
  u16* const ST = (u16*)(L + O_ST);            // [100][420]: [q][st*104+k]
  u16* const QC = (u16*)(L + O_Q);             // [100][196]
  u16* const KC = (u16*)(L + O_K);             // [100][196]
  // P1/P2 staging (in ST area)
  u16* const SA  = (u16*)(L + O_ST);           // [100][132]
  u16* const SW1 = (u16*)(L + O_ST + 26400);   // [64][132]
  u16* const SW2 = (u16*)(L + O_ST + 43296);   // [64][132]
  // P3 staging (in ST area)
  u16* const AT0  = (u16*)(L + O_ST);          // [100][68]
  u16* const AT1  = (u16*)(L + O_ST + 13600);
  u16* const WA0Q = (u16*)(L + O_ST + 27200);  // [32][68] x4
  u16* const WA0K = (u16*)(L + O_ST + 31552);
  u16* const WA1Q = (u16*)(L + O_ST + 35904);
  u16* const WA1K = (u16*)(L + O_ST + 40256);
  // gate phase
  u16* const W1T = (u16*)(L + O_K);            // [128][116], zero outside (c<100 && k<100)
  float* const e2s = (float*)(L + O_K + E2S);  // [400] raw gate logits
  // V phase
  u16* const VA  = (u16*)(L + O_Q);            // [100][132] (over dead QC)
  u16* const WVT = (u16*)(L + O_K);            // [64][132] (over dead W1T)
  u16* const VT  = (u16*)(L + O_K + 16896);    // [64][116], ends 31744 < e2s@32000

  const int tid = threadIdx.x;
  const int bh = blockIdx.x;
  const int b = bh >> 1, h = bh & 1;
  const size_t row0 = (size_t)b * Sd;
  const int l = tid & 63, w = tid >> 6;        // w in 0..15
  const int cr = l & 31, g = l >> 5;

  // ---------- S1: stage P1 operands; issue P2 loads (T14) ----------
  stage_rows4<5>(input + row0 * 128, SA, 100, AP, tid, NTHR);
  if constexpr (PREP) {
    copy_w64(wsw + WQT_E + h * 8192, SW1, tid, NTHR);
    copy_w64(wsw + WKT_E + h * 8192, SW2, tid, NTHR);
  } else {
    stage_wt6(Wq, h * 64, SW1, tid, NTHR);
    stage_wt6(Wk, h * 64, SW2, tid, NTHR);
  }
  float4 r2[8];  // PREP: 3200 pos float4 (r2[0..3]); else + Wqp/Wkp
#pragma unroll
  for (int s = 0; s < 8; ++s) {
    if (PREP && s >= 4) break;
    const int fi = tid + s * NTHR;
    if (fi < 3200) {
      r2[s] = ld4(posE + row0 * 128 + fi * 4);
    } else if (!PREP && fi < 5248) {
      const int f2 = fi - 3200, k = f2 >> 4, c0 = (f2 & 15) << 2;
      r2[s] = ld4(Wqp + k * 128 + h * 64 + c0);
    } else if (!PREP && fi < 7296) {
      const int f2 = fi - 5248, k = f2 >> 4, c0 = (f2 & 15) << 2;
      r2[s] = ld4(Wkp + k * 128 + h * 64 + c0);
    }
  }
  __syncthreads();

  // ---------- G1: Q/K projections ----------
  {
    const int pr = w >> 3, mt = (w >> 1) & 3, nt = w & 1;
    tile32<128, false>(SA, AP, pr ? SW2 : SW1, AP, (pr ? bk : bq) + h * 64,
                       pr ? KC : QC, QKP, 0, mt * 32, nt * 32, l);
  }
  __syncthreads();

  // ---------- S2: write r2 -> LDS; copy QP/KP weights; issue P3 loads ----------
#pragma unroll
  for (int s = 0; s < 8; ++s) {
    if (PREP && s >= 4) break;
    const int fi = tid + s * NTHR;
    if (fi < 3200) {
      ushort4 o;
      o.x = f2bu(r2[s].x); o.y = f2bu(r2[s].y); o.z = f2bu(r2[s].z); o.w = f2bu(r2[s].w);
      *reinterpret_cast<ushort4*>(SA + (fi >> 5) * AP + ((fi & 31) << 2)) = o;
    } else if (!PREP && fi < 5248) {
      const int f2 = fi - 3200, k = f2 >> 4, c0 = (f2 & 15) << 2;
      SW1[c0 * AP + k] = f2bu(r2[s].x); SW1[(c0 + 1) * AP + k] = f2bu(r2[s].y);
      SW1[(c0 + 2) * AP + k] = f2bu(r2[s].z); SW1[(c0 + 3) * AP + k] = f2bu(r2[s].w);
    } else if (!PREP && fi < 7296) {
      const int f2 = fi - 5248, k = f2 >> 4, c0 = (f2 & 15) << 2;
      SW2[c0 * AP + k] = f2bu(r2[s].x); SW2[(c0 + 1) * AP + k] = f2bu(r2[s].y);
      SW2[(c0 + 2) * AP + k] = f2bu(r2[s].z); SW2[(c0 + 3) * AP + k] = f2bu(r2[s].w);
    }
  }
  if constexpr (PREP) {
    copy_w64(wsw + WQPT_E + h * 8192, SW1, tid, NTHR);
    copy_w64(wsw + WKPT_E + h * 8192, SW2, tid, NTHR);
  }
  float4 r3[6];  // PREP: 3200 attr float4 (r3[0..3]); else + attr weights
#pragma unroll
  for (int s = 0; s < 6; ++s) {
    if (PREP && s >= 4) break;
    const int fi = tid + s * NTHR;
    if (fi < 1600) {
      r3[s] = ld4(attrT + (size_t)b * 6400 + fi * 4);
    } else if (fi < 3200) {
      r3[s] = ld4(attrT + (size_t)(B_ + b) * 6400 + (fi - 1600) * 4);
    } else if (!PREP && fi < 5248) {
      const int f3 = fi - 3200, which = f3 >> 9, fj = f3 & 511;
      const int k = fj >> 3, c0 = (fj & 7) << 2;
      const float* src = (which == 0) ? Wqa : (which == 1) ? Wka
                       : (which == 2) ? (Wqa + 4096) : (Wka + 4096);
      r3[s] = ld4(src + k * 64 + h * 32 + c0);
    }
  }
  __syncthreads();

  // ---------- G2: QP/KP projections ----------
  {
    const int pr = w >> 3, mt = (w >> 1) & 3, nt = w & 1;
    tile32<128, false>(SA, AP, pr ? SW2 : SW1, AP, (pr ? bkp : bqp) + h * 64,
                       pr ? KC : QC, QKP, 64, mt * 32, nt * 32, l);
  }
  __syncthreads();

  // ---------- S3: write r3 -> LDS; copy attr weights; issue W1 loads ----------
#pragma unroll
  for (int s = 0; s < 6; ++s) {
    if (PREP && s >= 4) break;
    const int fi = tid + s * NTHR;
    if (fi < 1600) {
      ushort4 o;
      o.x = f2bu(r3[s].x); o.y = f2bu(r3[s].y); o.z = f2bu(r3[s].z); o.w = f2bu(r3[s].w);
      *reinterpret_cast<ushort4*>(AT0 + (fi >> 4) * ATP + ((fi & 15) << 2)) = o;
    } else if (fi < 3200) {
      const int f3 = fi - 1600;
      ushort4 o;
      o.x = f2bu(r3[s].x); o.y = f2bu(r3[s].y); o.z = f2bu(r3[s].z); o.w = f2bu(r3[s].w);
      *reinterpret_cast<ushort4*>(AT1 + (f3 >> 4) * ATP + ((f3 & 15) << 2)) = o;
    } else if (!PREP && fi < 5248) {
      const int f3 = fi - 3200, which = f3 >> 9, fj = f3 & 511;
      const int k = fj >> 3, c0 = (fj & 7) << 2;
      u16* dst = (which == 0) ? WA0Q : (which == 1) ? WA0K
               : (which == 2) ? WA1Q : WA1K;
      dst[c0 * ATP + k] = f2bu(r3[s].x); dst[(c0 + 1) * ATP + k] = f2bu(r3[s].y);
      dst[(c0 + 2) * ATP + k] = f2bu(r3[s].z); dst[(c0 + 3) * ATP + k] = f2bu(r3[s].w);
    }
  }
  if constexpr (PREP) {
    for (int i = tid; i < 2048; i += NTHR) {  // WAT: [4pr][2h][32][64] -> [32][68] x4
      const int pr = i >> 9, row = (i >> 4) & 31, c4 = (i & 15) << 2;
      u16* dst = (pr == 0) ? WA0Q : (pr == 1) ? WA0K : (pr == 2) ? WA1Q : WA1K;
      *reinterpret_cast<ushort4*>(dst + row * ATP + c4) =
          *reinterpret_cast<const ushort4*>(wsw + WAT_E + pr * 4096 + h * 2048 + row * 64 + c4);
    }
  }
  float4 r5[3];    // fallback: W1 f32 (2500 float4)
  ushort4 rw1[4];  // PREP: W1T bf16 blob (3712 ushort4)
  if constexpr (PREP) {
#pragma unroll
    for (int s = 0; s < 4; ++s) {
      const int fi = tid + s * NTHR;
      if (fi < 3712) rw1[s] = reinterpret_cast<const ushort4*>(wsw + W1T_E)[fi];
    }
  } else {
#pragma unroll
    for (int s = 0; s < 3; ++s) {
      const int fi = tid + s * NTHR;
      if (fi < 2500) r5[s] = ld4(W1 + fi * 4);
    }
  }
  __syncthreads();

  // ---------- G3: attribute projections ----------
  {
    const int pr = w >> 2, mt = w & 3;  // 0=A0Q 1=A0K 2=A1Q 3=A1K
    const u16* Asrc = (pr < 2) ? AT0 : AT1;
    const u16* Wt = (pr == 0) ? WA0Q : (pr == 1) ? WA0K : (pr == 2) ? WA1Q : WA1K;
    const float* bs = (pr == 0) ? bqa + h * 32 : (pr == 1) ? bka + h * 32
                     : (pr == 2) ? bqa + 64 + h * 32 : bka + 64 + h * 32;
    tile32<64, false>(Asrc, ATP, Wt, ATP, bs, (pr & 1) ? KC : QC, QKP,
                      128 + (pr >> 1) * 32, mt * 32, 0, l);
  }
  __syncthreads();

  // ---------- G4: 4-stream scores -> ST (+ finite row pads 416..419) ----------
  {
    ushort4 z; z.x = z.y = z.z = z.w = 0;
    for (int q = tid; q < Sd; q += NTHR)
      *reinterpret_cast<ushort4*>(ST + q * STP + 416) = z;
  }
  {
    const int mt = w >> 2, nt = w & 3;
    const int m0 = mt * 32, n0 = nt * 32;
    int ar = m0 + cr; if (ar >= Sd) ar = Sd - 1;
    int br = n0 + cr; if (br >= Sd) br = Sd - 1;
    const u16* ap = QC + ar * QKP + g * 8;
    const u16* bp = KC + br * QKP + g * 8;
    f32x16 ai = zf16(), po = zf16(), a0 = zf16(), a1 = zf16();
    ai = MFMA32(ld8(ap + 0),   ld8(bp + 0),   ai);
    ai = MFMA32(ld8(ap + 16),  ld8(bp + 16),  ai);
    ai = MFMA32(ld8(ap + 32),  ld8(bp + 32),  ai);
    ai = MFMA32(ld8(ap + 48),  ld8(bp + 48),  ai);
    po = MFMA32(ld8(ap + 64),  ld8(bp + 64),  po);
    po = MFMA32(ld8(ap + 80),  ld8(bp + 80),  po);
    po = MFMA32(ld8(ap + 96),  ld8(bp + 96),  po);
    po = MFMA32(ld8(ap + 112), ld8(bp + 112), po);
    a0 = MFMA32(ld8(ap + 128), ld8(bp + 128), a0);
    a0 = MFMA32(ld8(ap + 144), ld8(bp + 144), a0);
    a1 = MFMA32(ld8(ap + 160), ld8(bp + 160), a1);
    a1 = MFMA32(ld8(ap + 176), ld8(bp + 176), a1);
    const int col = n0 + cr;
    if (col < STS) {  // writes pads 100..103 too (finite fill for gate k-spill)
#pragma unroll
      for (int i = 0; i < 16; ++i) {
        const int row = m0 + (i & 3) + 8 * (i >> 2) + 4 * g;
        if (row < Sd) {
          u16* sp = ST + row * STP + col;
          sp[0]       = f2bu(a0[i]);   // attr0
          sp[STS]     = f2bu(a1[i]);   // attr1
          sp[2 * STS] = f2bu(ai[i]);   // item
          sp[3 * STS] = f2bu(po[i]);   // pos
        }
      }
    }
  }
  __syncthreads();

  // ---------- S5: W1T into LDS ----------
  if constexpr (PREP) {
#pragma unroll
    for (int s = 0; s < 4; ++s) {  // blob already padded: flat contiguous copy
      const int fi = tid + s * NTHR;
      if (fi < 3712) reinterpret_cast<ushort4*>(W1T)[fi] = rw1[s];
    }
  } else {
    {
      ushort4 z; z.x = z.y = z.z = z.w = 0;
      if (tid < 812)
        *reinterpret_cast<ushort4*>(W1T + 11600 + tid * 4) = z;
      if (tid < 400) {
        const int c = tid >> 2, kq = 100 + ((tid & 3) << 2);
        *reinterpret_cast<ushort4*>(W1T + c * W1P + kq) = z;
      }
    }
#pragma unroll
    for (int s = 0; s < 3; ++s) {
      const int fi = tid + s * NTHR;
      if (fi < 2500) {
#pragma unroll
        for (int j = 0; j < 4; ++j) {
          const int o = fi * 4 + j;
          const int k = o / 100, c = o - k * 100;
          W1T[c * W1P + k] = f2bu((j == 0) ? r5[s].x : (j == 1) ? r5[s].y
                                  : (j == 2) ? r5[s].z : r5[s].w);
        }
      }
    }
  }
  if (tid < 8) ((u16*)(L + O_Q))[tid] = 0;  // guard: q=99/st=3 k-spill reads past ST
  __syncthreads();

  // ---------- G5: gate GEMM -> raw logits e2s ----------
  {
    float b1v[4], w2v[4];
#pragma unroll
    for (int nt = 0; nt < 4; ++nt) {
      const int c = nt * 32 + cr;
      b1v[nt] = (c < Sd) ? b1[c] : 0.f;
      w2v[nt] = (c < Sd) ? W2[c] : 0.f;
    }
    for (int mt = w; mt < 13; mt += NW) {
      const int m0 = mt * 32;
      int gr = m0 + cr; if (gr > 399) gr = 399;
      const u16* ap = ST + (gr >> 2) * STP + (gr & 3) * STS + g * 8;
      f32x16 c0 = zf16(), c1 = zf16(), c2 = zf16(), c3 = zf16();
#pragma unroll
      for (int k0 = 0; k0 < 112; k0 += 16) {
        const bf16x8 af = ld8(ap + k0);
        c0 = MFMA32(af, ld8(W1T + (cr)      * W1P + g * 8 + k0), c0);
        c1 = MFMA32(af, ld8(W1T + (32 + cr) * W1P + g * 8 + k0), c1);
        c2 = MFMA32(af, ld8(W1T + (64 + cr) * W1P + g * 8 + k0), c2);
        c3 = MFMA32(af, ld8(W1T + (96 + cr) * W1P + g * 8 + k0), c3);
      }
#pragma unroll
      for (int i = 0; i < 16; ++i) {
        float v = fmaxf(c0[i] + b1v[0], 0.f) * w2v[0]
                + fmaxf(c1[i] + b1v[1], 0.f) * w2v[1]
                + fmaxf(c2[i] + b1v[2], 0.f) * w2v[2]
                + fmaxf(c3[i] + b1v[3], 0.f) * w2v[3];
#pragma unroll
        for (int mm = 1; mm < 32; mm <<= 1) v += __shfl_xor(v, mm);
        if (cr == 0) {
          const int go = m0 + (i & 3) + 8 * (i >> 2) + 4 * g;
          if (go < 400) e2s[go] = v;
        }
      }
    }
  }
  __syncthreads();

  // ---------- P6 wave-split: waves 8-15 stage V operands || waves 0-7 softmax ----------
  if (w >= 8) {
    const int t2 = tid - 512;
    stage_rows4<5>(input + row0 * 128, VA, 100, AP, t2, 512);
    if constexpr (PREP) {
      copy_w64(wsw + WVT_E + h * 8192, WVT, t2, 512);
    } else {
      stage_wt6(Wv, h * 64, WVT, t2, 512);
    }
    ushort4 z; z.x = z.y = z.z = z.w = 0;
    for (int i2 = t2; i2 < 64 * VTP / 4; i2 += 512)
      *reinterpret_cast<ushort4*>(VT + i2 * 4) = z;
  } else {
    for (int q = w; q < Sd; q += 8) {
      const float* ez = e2s + q * 4;
      float e0 = ez[0], e1 = ez[1], e2v = ez[2], e3 = ez[3];
      const float mg = fmaxf(fmaxf(e0, e1), fmaxf(e2v, e3));
      e0 = __expf(e0 - mg); e1 = __expf(e1 - mg);
      e2v = __expf(e2v - mg); e3 = __expf(e3 - mg);
      const float ginv = 1.0f / (e0 + e1 + e2v + e3);
      const float g0v = e0 * ginv, g1v = e1 * ginv, g2v = e2v * ginv, g3v = e3 * ginv;
      u16* const sp = ST + q * STP;
      const float* const mp = mask + (size_t)b * 10000 + q * 100;
      float x1 = g0v * bfr(sp[l]) + g1v * bfr(sp[STS + l]) +
                 g2v * bfr(sp[2 * STS + l]) + g3v * bfr(sp[3 * STS + l]);
      x1 = x1 * 0.125f + mp[l];
      const bool v2 = (l < 36);
      float x2 = -3e38f;
      if (v2) {
        const int k2 = 64 + l;
        x2 = g0v * bfr(sp[k2]) + g1v * bfr(sp[STS + k2]) +
             g2v * bfr(sp[2 * STS + k2]) + g3v * bfr(sp[3 * STS + k2]);
        x2 = x2 * 0.125f + mp[k2];
      }
      const float M = wmax(fmaxf(x1, x2));
      const float ea = __expf(x1 - M);
      const float eb = v2 ? __expf(x2 - M) : 0.f;
      const float inv = 1.0f / wsum(ea + eb);
      sp[l] = f2bu(ea * inv);
      if (v2) sp[64 + l] = f2bu(eb * inv);
    }
  }
  __syncthreads();

  // ---------- G7: V projection -> VT[c][s] (LDS weights) ----------
  if (w < 8) {
    const int mt = w >> 1, nt = w & 1;
    tile32<128, true>(VA, AP, WVT, AP, bv + h * 64, VT, VTP, 0, mt * 32, nt * 32, l);
  }
  __syncthreads();

  // ---------- G8: PV -> ctx (global f32) ----------
  if (w < 8) {
    const int mt = w >> 1, nt = w & 1;
    const int m0 = mt * 32, n0 = nt * 32;
    int ar = m0 + cr; if (ar >= Sd) ar = Sd - 1;
    const u16* ap = ST + ar * STP + g * 8;
    const u16* bp = VT + (n0 + cr) * VTP + g * 8;
    f32x16 acc = zf16();
#pragma unroll
    for (int k0 = 0; k0 < 112; k0 += 16)
      acc = MFMA32(ld8(ap + k0), ld8(bp + k0), acc);
#pragma unroll
    for (int i = 0; i < 16; ++i) {
      const int row = m0 + (i & 3) + 8 * (i >> 2) + 4 * g;
      if (row < Sd)
        ctx[(row0 + row) * 128 + h * 64 + n0 + cr] = acc[i];
    }
  }
}

// ---------------------------------------------------------------------------
// Output dense (32x32 MFMA) + bias + residual + LayerNorm, in place over d_out.
// 512 threads, 128 rows/block, bf16 Hs.
// ---------------------------------------------------------------------------
template <bool PREP>
__global__ __launch_bounds__(512) void dense_ln(
    const float* __restrict__ ctxg, const float* __restrict__ Wd,
    const float* __restrict__ bd, const float* __restrict__ resid,
    const float* __restrict__ lng, const float* __restrict__ lnb,
    const u16* __restrict__ wsw, float* __restrict__ out) {
  __shared__ __align__(16) char L[101376];
  u16* const Ab  = (u16*)L;              // [128][132]
  u16* const WdT = (u16*)(L + 33792);    // [128][132]
  u16* const Hs  = (u16*)(L + 67584);    // [128][132] bf16 (GEMM term only)
  const int tid = threadIdx.x;
  const size_t row0 = (size_t)blockIdx.x * 128;
  const int l = tid & 63, w = tid >> 6, cr = l & 31, g = l >> 5;

  stage_rows4<5>(ctxg + row0 * 128, Ab, 128, AP, tid, 512);
  if constexpr (PREP) {
    for (int i = tid; i < 4096; i += 512) {
      const int r = i >> 5, c4 = (i & 31) << 2;
      *reinterpret_cast<ushort4*>(WdT + r * AP + c4) =
          *reinterpret_cast<const ushort4*>(wsw + WDT_E + r * 128 + c4);
    }
  } else {
    stage_wt<7>(Wd, 128, 0, WdT, 128, AP, tid, 512);
  }
  __syncthreads();

  for (int u = w; u < 16; u += 8) {
    const int m0 = (u >> 2) * 32, n0 = (u & 3) * 32;
    const u16* ap = Ab + (m0 + cr) * AP + g * 8;
    const u16* bp = WdT + (n0 + cr) * AP + g * 8;
    f32x16 acc = zf16();
#pragma unroll
    for (int k0 = 0; k0 < 128; k0 += 16)
      acc = MFMA32(ld8(ap + k0), ld8(bp + k0), acc);
#pragma unroll
    for (int i = 0; i < 16; ++i) {
      const int row = m0 + (i & 3) + 8 * (i >> 2) + 4 * g;
      Hs[row * AP + n0 + cr] = f2bu(acc[i]);
    }
  }
  __syncthreads();

  for (int rr = w; rr < 128; rr += 8) {
    const size_t grow = row0 + rr;
    const float h1 = bfr(Hs[rr * AP + l])      + bd[l]      + resid[grow * 128 + l];
    const float h2 = bfr(Hs[rr * AP + 64 + l]) + bd[64 + l] + resid[grow * 128 + 64 + l];
    const float mu = wsum(h1 + h2) * (1.0f / 128.0f);
    const float d1 = h1 - mu, d2 = h2 - mu;
    const float var = wsum(d1 * d1 + d2 * d2) * (1.0f / 128.0f);
    const float rs = rsqrtf(var + 1e-12f);
    out[grow * 128 + l]      = d1 * rs * lng[l]      + lnb[l];
    out[grow * 128 + 64 + l] = d2 * rs * lng[64 + l] + lnb[64 + l];
  }
}

}  // namespace

extern "C" void kernel_launch(void* const* d_in, const int* in_sizes, int n_in,
                              void* d_out, int out_size, void* d_ws,
                              size_t ws_size, hipStream_t stream) {
  (void)in_sizes; (void)n_in; (void)out_size;

  const float* input = (const float*)d_in[0];
  const float* attrT = (const float*)d_in[1];
  const float* posE  = (const float*)d_in[2];
  const float* mask  = (const float*)d_in[3];
  const float* Wq  = (const float*)d_in[4];  const float* bq  = (const float*)d_in[5];
  const float* Wk  = (const float*)d_in[6];  const float* bk  = (const float*)d_in[7];
  const float* Wv  = (const float*)d_in[8];  const float* bv  = (const float*)d_in[9];
  const float* Wqp = (const float*)d_in[10]; const float* bqp = (const float*)d_in[11];
  const float* Wkp = (const float*)d_in[12]; const float* bkp = (const float*)d_in[13];
  const float* Wqa = (const float*)d_in[14]; const float* bqa = (const float*)d_in[15];
  const float* Wka = (const float*)d_in[16]; const float* bka = (const float*)d_in[17];
  const float* W1  = (const float*)d_in[18]; const float* b1  = (const float*)d_in[19];
  const float* W2  = (const float*)d_in[20];
  const float* Wd  = (const float*)d_in[22]; const float* bd  = (const float*)d_in[23];
  const float* lng = (const float*)d_in[24]; const float* lnb = (const float*)d_in[25];

  float* ctx = (float*)d_out;  // d_out doubles as ctx staging, then final output

  if (ws_size >= WS_NEED) {
    u16* wsw = (u16*)d_ws;
    prep_weights<<<dim3(128), dim3(256), 0, stream>>>(
        Wq, Wk, Wqp, Wkp, Wv, Wqa, Wka, W1, Wd, wsw);
    attn_mega<true><<<dim3(B_ * 2), dim3(NTHR), 0, stream>>>(
        input, attrT, posE, mask, Wq, bq, Wk, bk, Wv, bv, Wqp, bqp, Wkp, bkp,
        Wqa, bqa, Wka, bka, W1, b1, W2, wsw, ctx);
    dense_ln<true><<<dim3(BS_ / 128), dim3(512), 0, stream>>>(
        ctx, Wd, bd, input, lng, lnb, wsw, ctx);
  } else {
    attn_mega<false><<<dim3(B_ * 2), dim3(NTHR), 0, stream>>>(
        input, attrT, posE, mask, Wq, bq, Wk, bk, Wv, bv, Wqp, bqp, Wkp, bkp,
        Wqa, bqa, Wka, bka, W1, b1, W2, nullptr, ctx);
    dense_ln<false><<<dim3(BS_ / 128), dim3(512), 0, stream>>>(
        ctx, Wd, bd, input, lng, lnb, nullptr, ctx);
  }
}

// Round 11
// 318.348 us; speedup vs baseline: 1.2473x; 1.1160x over previous
//
#include <hip/hip_runtime.h>
#include <hip/hip_bf16.h>

using bf16 = __hip_bfloat16;
using u16 = unsigned short;
typedef __attribute__((ext_vector_type(8))) short bf16x8;
typedef __attribute__((ext_vector_type(16))) float f32x16;

namespace {

constexpr int B_  = 1024;
constexpr int Sd  = 100;
constexpr int BS_ = B_ * Sd;

constexpr int NTHR = 1024;   // 16 waves -> 4 waves/SIMD
constexpr int NW   = 16;

constexpr int STP = 420;   // ST q-row pitch; 2-way bank alias (free)
constexpr int STS = 104;   // per-stream pitch inside a q-row
constexpr int QKP = 196;   // QC/KC pitch
constexpr int AP  = 132;   // 128-wide staging pitch
constexpr int ATP = 68;    // 64-wide attr staging pitch
constexpr int W1P = 116;   // W1T pitch (112 would be 8-way conflict)
constexpr int VTP = 116;

constexpr int O_ST = 0;        // ST [100][420] = 84,000 B (P1-P3: staging scratch)
constexpr int O_Q  = 84000;    // QC [100][196] = 39,200 (P6+: VA [100][132])
constexpr int O_K  = 123200;   // KC [100][196] = 39,200 (G5: W1T+e2s; P6+: WVT, VT, e2s)
constexpr int E2S  = 32000;    // e2s f32[400] at O_K+32000 (dead-KC tail; > VT end 31744)
constexpr int LBYTES = 162400;

// d_ws bf16 blob element offsets (prep_weights layout)
constexpr int WQT_E  = 0;        // [2h][64c][128k]
constexpr int WKT_E  = 16384;
constexpr int WQPT_E = 32768;
constexpr int WKPT_E = 49152;
constexpr int WVT_E  = 65536;
constexpr int WAT_E  = 81920;    // [4pr][2h][32c][64k]
constexpr int W1T_E  = 98304;    // [128c][116k] incl. zero pads
constexpr int WDT_E  = 113152;   // [128c][128k]
constexpr size_t WS_NEED = 129536ull * 2;  // 259,072 B

__device__ __forceinline__ float bfr(u16 u) {
  unsigned int x = ((unsigned int)u) << 16;
  float f; __builtin_memcpy(&f, &x, 4); return f;
}
__device__ __forceinline__ u16 f2bu(float x) {
  bf16 h = __float2bfloat16(x);
  u16 u; __builtin_memcpy(&u, &h, 2); return u;
}
__device__ __forceinline__ float4 ld4(const float* p) {
  return *reinterpret_cast<const float4*>(p);
}
__device__ __forceinline__ float wsum(float v) {
#pragma unroll
  for (int m = 32; m > 0; m >>= 1) v += __shfl_xor(v, m);
  return v;
}
__device__ __forceinline__ float wmax(float v) {
#pragma unroll
  for (int m = 32; m > 0; m >>= 1) v = fmaxf(v, __shfl_xor(v, m));
  return v;
}
__device__ __forceinline__ f32x16 zf16() {
  f32x16 z;
#pragma unroll
  for (int i = 0; i < 16; ++i) z[i] = 0.f;
  return z;
}
__device__ __forceinline__ f32x16 MFMA32(bf16x8 a, bf16x8 b, f32x16 c) {
  return __builtin_amdgcn_mfma_f32_32x32x16_bf16(a, b, c, 0, 0, 0);
}

// 8 contiguous bf16, 8B-aligned (LDS): two b64 reads. Same helper for A and B
// operands -> any k-permutation inside the 16-block cancels in the MFMA.
__device__ __forceinline__ bf16x8 ld8(const u16* p) {
  const ushort4 a = *reinterpret_cast<const ushort4*>(p);
  const ushort4 b = *reinterpret_cast<const ushort4*>(p + 4);
  bf16x8 f;
  f[0] = (short)a.x; f[1] = (short)a.y; f[2] = (short)a.z; f[3] = (short)a.w;
  f[4] = (short)b.x; f[5] = (short)b.y; f[6] = (short)b.z; f[7] = (short)b.w;
  return f;
}

// global f32 rows (contiguous, ncol = 4<<L4) -> LDS bf16 [nrow][pitch]
template <int L4>
__device__ __forceinline__ void stage_rows4(const float* __restrict__ src, u16* dst,
                                            int nrow, int pitch, int tid, int nthr) {
  for (int i = tid; i < (nrow << L4); i += nthr) {
    const int rr = i >> L4, cc = (i & ((1 << L4) - 1)) << 2;
    const float4 v = *reinterpret_cast<const float4*>(src + ((size_t)rr << (L4 + 2)) + cc);
    ushort4 o;
    o.x = f2bu(v.x); o.y = f2bu(v.y); o.z = f2bu(v.z); o.w = f2bu(v.w);
    *reinterpret_cast<ushort4*>(dst + rr * pitch + cc) = o;
  }
}
// W[k][coff+c] -> WT[c][k] bf16 (fallback path only)
template <int LC>
__device__ __forceinline__ void stage_wt(const float* __restrict__ W, int ldw, int coff,
                                         u16* dst, int kd, int pitch, int tid, int nthr) {
  constexpr int NC = 1 << LC;
  for (int idx = tid; idx < NC * kd; idx += nthr) {
    const int k = idx >> LC, c = idx & (NC - 1);
    dst[c * pitch + k] = f2bu(W[k * ldw + coff + c]);
  }
}
__device__ __forceinline__ void stage_wt6(const float* __restrict__ W, int coff,
                                          u16* dst, int tid, int nthr) {
  stage_wt<6>(W, 128, coff, dst, 128, AP, tid, nthr);
}
// ws bf16 [64][128] blob -> LDS [64][AP] (vectorized copy)
__device__ __forceinline__ void copy_w64(const u16* __restrict__ src, u16* dst,
                                         int tid, int nthr) {
  for (int i = tid; i < 2048; i += nthr) {
    const int r = i >> 5, c4 = (i & 31) << 2;
    *reinterpret_cast<ushort4*>(dst + r * AP + c4) =
        *reinterpret_cast<const ushort4*>(src + r * 128 + c4);
  }
}

// One 32x32 output tile: dst = A[100][KD] @ Wt[N][KD]^T + bias.
// TR=false: dst[row][dbase+n0+col]; TR=true: dst[n0+col][dbase+row].
template <int KD, bool TR>
__device__ __forceinline__ void tile32(const u16* A, int apitch, const u16* Wt, int wpitch,
                                       const float* __restrict__ bias, u16* dst, int dpitch,
                                       int dbase, int m0, int n0, int l) {
  const int cr = l & 31, g = l >> 5;
  int ar = m0 + cr; if (ar >= Sd) ar = Sd - 1;
  const u16* ap = A + ar * apitch + g * 8;
  const u16* bp = Wt + (n0 + cr) * wpitch + g * 8;
  f32x16 acc = zf16();
#pragma unroll
  for (int k0 = 0; k0 < KD; k0 += 16)
    acc = MFMA32(ld8(ap + k0), ld8(bp + k0), acc);
  const float bvv = bias[n0 + cr];
#pragma unroll
  for (int i = 0; i < 16; ++i) {
    const int row = m0 + (i & 3) + 8 * (i >> 2) + 4 * g;  // C/D: col=lane&31 (measured)
    if (row < Sd) {
      if (TR) dst[(n0 + cr) * dpitch + dbase + row] = f2bu(acc[i] + bvv);
      else    dst[row * dpitch + dbase + n0 + cr]   = f2bu(acc[i] + bvv);
    }
  }
}

// ---------------------------------------------------------------------------
// Weight preprocessing: f32 global -> bf16 transposed/padded blobs in d_ws.
// ---------------------------------------------------------------------------
__global__ __launch_bounds__(256) void prep_weights(
    const float* __restrict__ Wq, const float* __restrict__ Wk,
    const float* __restrict__ Wqp, const float* __restrict__ Wkp,
    const float* __restrict__ Wv, const float* __restrict__ Wqa,
    const float* __restrict__ Wka, const float* __restrict__ W1,
    const float* __restrict__ Wd, u16* __restrict__ ws) {
  const int t = blockIdx.x * 256 + threadIdx.x;
  const int NT = gridDim.x * 256;
  const float* srcs[5] = {Wq, Wk, Wqp, Wkp, Wv};
#pragma unroll
  for (int wsel = 0; wsel < 5; ++wsel) {
    u16* dst = ws + wsel * 16384;
    const float* src = srcs[wsel];
    for (int i = t; i < 16384; i += NT) {
      const int h = i >> 13, c = (i >> 7) & 63, k = i & 127;
      dst[i] = f2bu(src[k * 128 + h * 64 + c]);
    }
  }
  for (int i = t; i < 16384; i += NT) {
    const int pr = i >> 12, h = (i >> 11) & 1, c = (i >> 6) & 31, k = i & 63;
    const float* src = (pr & 1) ? Wka : Wqa;
    ws[WAT_E + i] = f2bu(src[(pr >> 1) * 4096 + k * 64 + h * 32 + c]);
  }
  for (int i = t; i < 14848; i += NT) {
    const int c = i / W1P, k = i - c * W1P;
    ws[W1T_E + i] = (c < Sd && k < Sd) ? f2bu(W1[k * Sd + c]) : (u16)0;
  }
  for (int i = t; i < 16384; i += NT) {
    const int c = i >> 7, k = i & 127;
    ws[WDT_E + i] = f2bu(Wd[k * 128 + c]);
  }
}

// ---------------------------------------------------------------------------
// Mega-kernel: Round-6/7 structure; P6 uses in-phase T14 (issue-early loads,
// softmax from registers, write-late staging). 16 waves full-width everywhere.
// ---------------------------------------------------------------------------
template <bool PREP>
__global__ __launch_bounds__(NTHR) void attn_mega(
    const float* __restrict__ input, const float* __restrict__ attrT,
    const float* __restrict__ posE, const float* __restrict__ mask,
    const float* __restrict__ Wq, const float* __restrict__ bq,
    const float* __restrict__ Wk, const float* __restrict__ bk,
    const float* __restrict__ Wv, const float* __restrict__ bv,
    const float* __restrict__ Wqp, const float* __restrict__ bqp,
    const float* __restrict__ Wkp, const float* __restrict__ bkp,
    const float* __restrict__ Wqa, const float* __restrict__ bqa,
    const float* __restrict__ Wka, const float* __restrict__ bka,
    const float* __restrict__ W1, const float* __restrict__ b1,
    const float* __restrict__ W2, const u16* __restrict__ wsw,
    float* __restrict__ ctx) {
  __shared__ __align__(16) char L[LBYTES];
  u16* const ST = (u16*)(L + O_ST);            // [100][420]: [q][st*104+k]
  u16* const QC = (u16*)(L + O_Q);             // [100][196]
  u16* const KC = (u16*)(L + O_K);             // [100][196]
  // P1/P2 staging (in ST area)
  u16* const SA  = (u16*)(L + O_ST);           // [100][132]
  u16* const SW1 = (u16*)(L + O_ST + 26400);   // [64][132]
  u16* const SW2 = (u16*)(L + O_ST + 43296);   // [64][132]
  // P3 staging (in ST area)
  u16* const AT0  = (u16*)(L + O_ST);          // [100][68]
  u16* const AT1  = (u16*)(L + O_ST + 13600);
  u16* const WA0Q = (u16*)(L + O_ST + 27200);  // [32][68] x4
  u16* const WA0K = (u16*)(L + O_ST + 31552);
  u16* const WA1Q = (u16*)(L + O_ST + 35904);
  u16* const WA1K = (u16*)(L + O_ST + 40256);
  // gate phase
  u16* const W1T = (u16*)(L + O_K);            // [128][116], zero outside (c<100 && k<100)
  float* const e2s = (float*)(L + O_K + E2S);  // [400] raw gate logits
  // V phase
  u16* const VA  = (u16*)(L + O_Q);            // [100][132] (over dead QC)
  u16* const WVT = (u16*)(L + O_K);            // [64][132] (over dead W1T)
  u16* const VT  = (u16*)(L + O_K + 16896);    // [64][116], ends 31744 < e2s@32000

  const int tid = threadIdx.x;
  const int bh = blockIdx.x;
  const int b = bh >> 1, h = bh & 1;
  const size_t row0 = (size_t)b * Sd;
  const int l = tid & 63, w = tid >> 6;        // w in 0..15
  const int cr = l & 31, g = l >> 5;

  // ---------- S1: stage P1 operands; issue P2 loads (T14) ----------
  stage_rows4<5>(input + row0 * 128, SA, 100, AP, tid, NTHR);
  if constexpr (PREP) {
    copy_w64(wsw + WQT_E + h * 8192, SW1, tid, NTHR);
    copy_w64(wsw + WKT_E + h * 8192, SW2, tid, NTHR);
  } else {
    stage_wt6(Wq, h * 64, SW1, tid, NTHR);
    stage_wt6(Wk, h * 64, SW2, tid, NTHR);
  }
  float4 r2[8];  // PREP: 3200 pos float4 (r2[0..3]); else + Wqp/Wkp
#pragma unroll
  for (int s = 0; s < 8; ++s) {
    if (PREP && s >= 4) break;
    const int fi = tid + s * NTHR;
    if (fi < 3200) {
      r2[s] = ld4(posE + row0 * 128 + fi * 4);
    } else if (!PREP && fi < 5248) {
      const int f2 = fi - 3200, k = f2 >> 4, c0 = (f2 & 15) << 2;
      r2[s] = ld4(Wqp + k * 128 + h * 64 + c0);
    } else if (!PREP && fi < 7296) {
      const int f2 = fi - 5248, k = f2 >> 4, c0 = (f2 & 15) << 2;
      r2[s] = ld4(Wkp + k * 128 + h * 64 + c0);
    }
  }
  __syncthreads();

  // ---------- G1: Q/K projections ----------
  {
    const int pr = w >> 3, mt = (w >> 1) & 3, nt = w & 1;
    tile32<128, false>(SA, AP, pr ? SW2 : SW1, AP, (pr ? bk : bq) + h * 64,
                       pr ? KC : QC, QKP, 0, mt * 32, nt * 32, l);
  }
  __syncthreads();

  // ---------- S2: write r2 -> LDS; copy QP/KP weights; issue P3 loads ----------
#pragma unroll
  for (int s = 0; s < 8; ++s) {
    if (PREP && s >= 4) break;
    const int fi = tid + s * NTHR;
    if (fi < 3200) {
      ushort4 o;
      o.x = f2bu(r2[s].x); o.y = f2bu(r2[s].y); o.z = f2bu(r2[s].z); o.w = f2bu(r2[s].w);
      *reinterpret_cast<ushort4*>(SA + (fi >> 5) * AP + ((fi & 31) << 2)) = o;
    } else if (!PREP && fi < 5248) {
      const int f2 = fi - 3200, k = f2 >> 4, c0 = (f2 & 15) << 2;
      SW1[c0 * AP + k] = f2bu(r2[s].x); SW1[(c0 + 1) * AP + k] = f2bu(r2[s].y);
      SW1[(c0 + 2) * AP + k] = f2bu(r2[s].z); SW1[(c0 + 3) * AP + k] = f2bu(r2[s].w);
    } else if (!PREP && fi < 7296) {
      const int f2 = fi - 5248, k = f2 >> 4, c0 = (f2 & 15) << 2;
      SW2[c0 * AP + k] = f2bu(r2[s].x); SW2[(c0 + 1) * AP + k] = f2bu(r2[s].y);
      SW2[(c0 + 2) * AP + k] = f2bu(r2[s].z); SW2[(c0 + 3) * AP + k] = f2bu(r2[s].w);
    }
  }
  if constexpr (PREP) {
    copy_w64(wsw + WQPT_E + h * 8192, SW1, tid, NTHR);
    copy_w64(wsw + WKPT_E + h * 8192, SW2, tid, NTHR);
  }
  float4 r3[6];  // PREP: 3200 attr float4 (r3[0..3]); else + attr weights
#pragma unroll
  for (int s = 0; s < 6; ++s) {
    if (PREP && s >= 4) break;
    const int fi = tid + s * NTHR;
    if (fi < 1600) {
      r3[s] = ld4(attrT + (size_t)b * 6400 + fi * 4);
    } else if (fi < 3200) {
      r3[s] = ld4(attrT + (size_t)(B_ + b) * 6400 + (fi - 1600) * 4);
    } else if (!PREP && fi < 5248) {
      const int f3 = fi - 3200, which = f3 >> 9, fj = f3 & 511;
      const int k = fj >> 3, c0 = (fj & 7) << 2;
      const float* src = (which == 0) ? Wqa : (which == 1) ? Wka
                       : (which == 2) ? (Wqa + 4096) : (Wka + 4096);
      r3[s] = ld4(src + k * 64 + h * 32 + c0);
    }
  }
  __syncthreads();

  // ---------- G2: QP/KP projections ----------
  {
    const int pr = w >> 3, mt = (w >> 1) & 3, nt = w & 1;
    tile32<128, false>(SA, AP, pr ? SW2 : SW1, AP, (pr ? bkp : bqp) + h * 64,
                       pr ? KC : QC, QKP, 64, mt * 32, nt * 32, l);
  }
  __syncthreads();

  // ---------- S3: write r3 -> LDS; copy attr weights; issue W1 loads ----------
#pragma unroll
  for (int s = 0; s < 6; ++s) {
    if (PREP && s >= 4) break;
    const int fi = tid + s * NTHR;
    if (fi < 1600) {
      ushort4 o;
      o.x = f2bu(r3[s].x); o.y = f2bu(r3[s].y); o.z = f2bu(r3[s].z); o.w = f2bu(r3[s].w);
      *reinterpret_cast<ushort4*>(AT0 + (fi >> 4) * ATP + ((fi & 15) << 2)) = o;
    } else if (fi < 3200) {
      const int f3 = fi - 1600;
      ushort4 o;
      o.x = f2bu(r3[s].x); o.y = f2bu(r3[s].y); o.z = f2bu(r3[s].z); o.w = f2bu(r3[s].w);
      *reinterpret_cast<ushort4*>(AT1 + (f3 >> 4) * ATP + ((f3 & 15) << 2)) = o;
    } else if (!PREP && fi < 5248) {
      const int f3 = fi - 3200, which = f3 >> 9, fj = f3 & 511;
      const int k = fj >> 3, c0 = (fj & 7) << 2;
      u16* dst = (which == 0) ? WA0Q : (which == 1) ? WA0K
               : (which == 2) ? WA1Q : WA1K;
      dst[c0 * ATP + k] = f2bu(r3[s].x); dst[(c0 + 1) * ATP + k] = f2bu(r3[s].y);
      dst[(c0 + 2) * ATP + k] = f2bu(r3[s].z); dst[(c0 + 3) * ATP + k] = f2bu(r3[s].w);
    }
  }
  if constexpr (PREP) {
    for (int i = tid; i < 2048; i += NTHR) {  // WAT: [4pr][2h][32][64] -> [32][68] x4
      const int pr = i >> 9, row = (i >> 4) & 31, c4 = (i & 15) << 2;
      u16* dst = (pr == 0) ? WA0Q : (pr == 1) ? WA0K : (pr == 2) ? WA1Q : WA1K;
      *reinterpret_cast<ushort4*>(dst + row * ATP + c4) =
          *reinterpret_cast<const ushort4*>(wsw + WAT_E + pr * 4096 + h * 2048 + row * 64 + c4);
    }
  }
  float4 r5[3];    // fallback: W1 f32 (2500 float4)
  ushort4 rw1[4];  // PREP: W1T bf16 blob (3712 ushort4)
  if constexpr (PREP) {
#pragma unroll
    for (int s = 0; s < 4; ++s) {
      const int fi = tid + s * NTHR;
      if (fi < 3712) rw1[s] = reinterpret_cast<const ushort4*>(wsw + W1T_E)[fi];
    }
  } else {
#pragma unroll
    for (int s = 0; s < 3; ++s) {
      const int fi = tid + s * NTHR;
      if (fi < 2500) r5[s] = ld4(W1 + fi * 4);
    }
  }
  __syncthreads();

  // ---------- G3: attribute projections ----------
  {
    const int pr = w >> 2, mt = w & 3;  // 0=A0Q 1=A0K 2=A1Q 3=A1K
    const u16* Asrc = (pr < 2) ? AT0 : AT1;
    const u16* Wt = (pr == 0) ? WA0Q : (pr == 1) ? WA0K : (pr == 2) ? WA1Q : WA1K;
    const float* bs = (pr == 0) ? bqa + h * 32 : (pr == 1) ? bka + h * 32
                     : (pr == 2) ? bqa + 64 + h * 32 : bka + 64 + h * 32;
    tile32<64, false>(Asrc, ATP, Wt, ATP, bs, (pr & 1) ? KC : QC, QKP,
                      128 + (pr >> 1) * 32, mt * 32, 0, l);
  }
  __syncthreads();

  // ---------- G4: 4-stream scores -> ST (+ finite row pads 416..419) ----------
  {
    ushort4 z; z.x = z.y = z.z = z.w = 0;
    for (int q = tid; q < Sd; q += NTHR)
      *reinterpret_cast<ushort4*>(ST + q * STP + 416) = z;
  }
  {
    const int mt = w >> 2, nt = w & 3;
    const int m0 = mt * 32, n0 = nt * 32;
    int ar = m0 + cr; if (ar >= Sd) ar = Sd - 1;
    int br = n0 + cr; if (br >= Sd) br = Sd - 1;
    const u16* ap = QC + ar * QKP + g * 8;
    const u16* bp = KC + br * QKP + g * 8;
    f32x16 ai = zf16(), po = zf16(), a0 = zf16(), a1 = zf16();
    ai = MFMA32(ld8(ap + 0),   ld8(bp + 0),   ai);
    ai = MFMA32(ld8(ap + 16),  ld8(bp + 16),  ai);
    ai = MFMA32(ld8(ap + 32),  ld8(bp + 32),  ai);
    ai = MFMA32(ld8(ap + 48),  ld8(bp + 48),  ai);
    po = MFMA32(ld8(ap + 64),  ld8(bp + 64),  po);
    po = MFMA32(ld8(ap + 80),  ld8(bp + 80),  po);
    po = MFMA32(ld8(ap + 96),  ld8(bp + 96),  po);
    po = MFMA32(ld8(ap + 112), ld8(bp + 112), po);
    a0 = MFMA32(ld8(ap + 128), ld8(bp + 128), a0);
    a0 = MFMA32(ld8(ap + 144), ld8(bp + 144), a0);
    a1 = MFMA32(ld8(ap + 160), ld8(bp + 160), a1);
    a1 = MFMA32(ld8(ap + 176), ld8(bp + 176), a1);
    const int col = n0 + cr;
    if (col < STS) {  // writes pads 100..103 too (finite fill for gate k-spill)
#pragma unroll
      for (int i = 0; i < 16; ++i) {
        const int row = m0 + (i & 3) + 8 * (i >> 2) + 4 * g;
        if (row < Sd) {
          u16* sp = ST + row * STP + col;
          sp[0]       = f2bu(a0[i]);   // attr0
          sp[STS]     = f2bu(a1[i]);   // attr1
          sp[2 * STS] = f2bu(ai[i]);   // item
          sp[3 * STS] = f2bu(po[i]);   // pos
        }
      }
    }
  }
  __syncthreads();

  // ---------- S5: W1T into LDS ----------
  if constexpr (PREP) {
#pragma unroll
    for (int s = 0; s < 4; ++s) {  // blob already padded: flat contiguous copy
      const int fi = tid + s * NTHR;
      if (fi < 3712) reinterpret_cast<ushort4*>(W1T)[fi] = rw1[s];
    }
  } else {
    {
      ushort4 z; z.x = z.y = z.z = z.w = 0;
      if (tid < 812)
        *reinterpret_cast<ushort4*>(W1T + 11600 + tid * 4) = z;
      if (tid < 400) {
        const int c = tid >> 2, kq = 100 + ((tid & 3) << 2);
        *reinterpret_cast<ushort4*>(W1T + c * W1P + kq) = z;
      }
    }
#pragma unroll
    for (int s = 0; s < 3; ++s) {
      const int fi = tid + s * NTHR;
      if (fi < 2500) {
#pragma unroll
        for (int j = 0; j < 4; ++j) {
          const int o = fi * 4 + j;
          const int k = o / 100, c = o - k * 100;
          W1T[c * W1P + k] = f2bu((j == 0) ? r5[s].x : (j == 1) ? r5[s].y
                                  : (j == 2) ? r5[s].z : r5[s].w);
        }
      }
    }
  }
  if (tid < 8) ((u16*)(L + O_Q))[tid] = 0;  // guard: q=99/st=3 k-spill reads past ST
  __syncthreads();

  // ---------- G5: gate GEMM -> raw logits e2s ----------
  {
    float b1v[4], w2v[4];
#pragma unroll
    for (int nt = 0; nt < 4; ++nt) {
      const int c = nt * 32 + cr;
      b1v[nt] = (c < Sd) ? b1[c] : 0.f;
      w2v[nt] = (c < Sd) ? W2[c] : 0.f;
    }
    for (int mt = w; mt < 13; mt += NW) {
      const int m0 = mt * 32;
      int gr = m0 + cr; if (gr > 399) gr = 399;
      const u16* ap = ST + (gr >> 2) * STP + (gr & 3) * STS + g * 8;
      f32x16 c0 = zf16(), c1 = zf16(), c2 = zf16(), c3 = zf16();
#pragma unroll
      for (int k0 = 0; k0 < 112; k0 += 16) {
        const bf16x8 af = ld8(ap + k0);
        c0 = MFMA32(af, ld8(W1T + (cr)      * W1P + g * 8 + k0), c0);
        c1 = MFMA32(af, ld8(W1T + (32 + cr) * W1P + g * 8 + k0), c1);
        c2 = MFMA32(af, ld8(W1T + (64 + cr) * W1P + g * 8 + k0), c2);
        c3 = MFMA32(af, ld8(W1T + (96 + cr) * W1P + g * 8 + k0), c3);
      }
#pragma unroll
      for (int i = 0; i < 16; ++i) {
        float v = fmaxf(c0[i] + b1v[0], 0.f) * w2v[0]
                + fmaxf(c1[i] + b1v[1], 0.f) * w2v[1]
                + fmaxf(c2[i] + b1v[2], 0.f) * w2v[2]
                + fmaxf(c3[i] + b1v[3], 0.f) * w2v[3];
#pragma unroll
        for (int mm = 1; mm < 32; mm <<= 1) v += __shfl_xor(v, mm);
        if (cr == 0) {
          const int go = m0 + (i & 3) + 8 * (i >> 2) + 4 * g;
          if (go < 400) e2s[go] = v;
        }
      }
    }
  }
  __syncthreads();

  // ---------- P6: T14 in-phase split — issue loads, softmax from regs, write-late ----------
  {
    // (a) issue VA (input re-read, L2-hot) + WVT (ws blob, L2-hot) loads into regs
    float4 va[4];
#pragma unroll
    for (int s = 0; s < 4; ++s) {
      const int fi = tid + s * NTHR;
      if (fi < 3200) va[s] = ld4(input + row0 * 128 + fi * 4);
    }
    ushort4 wv[2];
    if constexpr (PREP) {
#pragma unroll
      for (int s = 0; s < 2; ++s)
        wv[s] = reinterpret_cast<const ushort4*>(wsw + WVT_E + h * 8192)[tid + s * NTHR];
    }
    // (a2) issue all mask-row loads for this wave's softmax rows
    float m1r[7], m2r[7];
#pragma unroll
    for (int it = 0; it < 7; ++it) {
      const int q = w + it * NW;
      if (q < Sd) {
        const float* mp = mask + (size_t)b * 10000 + q * 100;
        m1r[it] = mp[l];
        m2r[it] = (l < 36) ? mp[64 + l] : 0.f;
      }
    }
    // (b) zero VT pads/body (LDS only)
    {
      ushort4 z; z.x = z.y = z.z = z.w = 0;
      for (int i2 = tid; i2 < 64 * VTP / 4; i2 += NTHR)
        *reinterpret_cast<ushort4*>(VT + i2 * 4) = z;
    }
    // (c) softmax: gate normalize + fuse + scale + mask + row softmax (regs/LDS only)
#pragma unroll
    for (int it = 0; it < 7; ++it) {
      const int q = w + it * NW;
      if (q < Sd) {
        const float* ez = e2s + q * 4;
        float e0 = ez[0], e1 = ez[1], e2v = ez[2], e3 = ez[3];
        const float mg = fmaxf(fmaxf(e0, e1), fmaxf(e2v, e3));
        e0 = __expf(e0 - mg); e1 = __expf(e1 - mg);
        e2v = __expf(e2v - mg); e3 = __expf(e3 - mg);
        const float ginv = 1.0f / (e0 + e1 + e2v + e3);
        const float g0v = e0 * ginv, g1v = e1 * ginv, g2v = e2v * ginv, g3v = e3 * ginv;
        u16* const sp = ST + q * STP;
        float x1 = g0v * bfr(sp[l]) + g1v * bfr(sp[STS + l]) +
                   g2v * bfr(sp[2 * STS + l]) + g3v * bfr(sp[3 * STS + l]);
        x1 = x1 * 0.125f + m1r[it];
        const bool v2 = (l < 36);
        float x2 = -3e38f;
        if (v2) {
          const int k2 = 64 + l;
          x2 = g0v * bfr(sp[k2]) + g1v * bfr(sp[STS + k2]) +
               g2v * bfr(sp[2 * STS + k2]) + g3v * bfr(sp[3 * STS + k2]);
          x2 = x2 * 0.125f + m2r[it];
        }
        const float M = wmax(fmaxf(x1, x2));
        const float ea = __expf(x1 - M);
        const float eb = v2 ? __expf(x2 - M) : 0.f;
        const float inv = 1.0f / wsum(ea + eb);
        sp[l] = f2bu(ea * inv);
        if (v2) sp[64 + l] = f2bu(eb * inv);
      }
    }
    // (d) write-late: VA regs -> LDS; WVT regs -> LDS (loads long since landed)
#pragma unroll
    for (int s = 0; s < 4; ++s) {
      const int fi = tid + s * NTHR;
      if (fi < 3200) {
        ushort4 o;
        o.x = f2bu(va[s].x); o.y = f2bu(va[s].y); o.z = f2bu(va[s].z); o.w = f2bu(va[s].w);
        *reinterpret_cast<ushort4*>(VA + (fi >> 5) * AP + ((fi & 31) << 2)) = o;
      }
    }
    if constexpr (PREP) {
#pragma unroll
      for (int s = 0; s < 2; ++s) {
        const int i2 = tid + s * NTHR;
        const int r = i2 >> 5, c4 = (i2 & 31) << 2;
        *reinterpret_cast<ushort4*>(WVT + r * AP + c4) = wv[s];
      }
    } else {
      stage_wt6(Wv, h * 64, WVT, tid, NTHR);
    }
  }
  __syncthreads();

  // ---------- G7: V projection -> VT[c][s] (LDS weights) ----------
  if (w < 8) {
    const int mt = w >> 1, nt = w & 1;
    tile32<128, true>(VA, AP, WVT, AP, bv + h * 64, VT, VTP, 0, mt * 32, nt * 32, l);
  }
  __syncthreads();

  // ---------- G8: PV -> ctx (global f32) ----------
  if (w < 8) {
    const int mt = w >> 1, nt = w & 1;
    const int m0 = mt * 32, n0 = nt * 32;
    int ar = m0 + cr; if (ar >= Sd) ar = Sd - 1;
    const u16* ap = ST + ar * STP + g * 8;
    const u16* bp = VT + (n0 + cr) * VTP + g * 8;
    f32x16 acc = zf16();
#pragma unroll
    for (int k0 = 0; k0 < 112; k0 += 16)
      acc = MFMA32(ld8(ap + k0), ld8(bp + k0), acc);
#pragma unroll
    for (int i = 0; i < 16; ++i) {
      const int row = m0 + (i & 3) + 8 * (i >> 2) + 4 * g;
      if (row < Sd)
        ctx[(row0 + row) * 128 + h * 64 + n0 + cr] = acc[i];
    }
  }
}

// ---------------------------------------------------------------------------
// Output dense (32x32 MFMA) + bias + residual + LayerNorm, in place over d_out.
// 512 threads, 128 rows/block, bf16 Hs.
// ---------------------------------------------------------------------------
template <bool PREP>
__global__ __launch_bounds__(512) void dense_ln(
    const float* __restrict__ ctxg, const float* __restrict__ Wd,
    const float* __restrict__ bd, const float* __restrict__ resid,
    const float* __restrict__ lng, const float* __restrict__ lnb,
    const u16* __restrict__ wsw, float* __restrict__ out) {
  __shared__ __align__(16) char L[101376];
  u16* const Ab  = (u16*)L;              // [128][132]
  u16* const WdT = (u16*)(L + 33792);    // [128][132]
  u16* const Hs  = (u16*)(L + 67584);    // [128][132] bf16 (GEMM term only)
  const int tid = threadIdx.x;
  const size_t row0 = (size_t)blockIdx.x * 128;
  const int l = tid & 63, w = tid >> 6, cr = l & 31, g = l >> 5;

  stage_rows4<5>(ctxg + row0 * 128, Ab, 128, AP, tid, 512);
  if constexpr (PREP) {
    for (int i = tid; i < 4096; i += 512) {
      const int r = i >> 5, c4 = (i & 31) << 2;
      *reinterpret_cast<ushort4*>(WdT + r * AP + c4) =
          *reinterpret_cast<const ushort4*>(wsw + WDT_E + r * 128 + c4);
    }
  } else {
    stage_wt<7>(Wd, 128, 0, WdT, 128, AP, tid, 512);
  }
  __syncthreads();

  for (int u = w; u < 16; u += 8) {
    const int m0 = (u >> 2) * 32, n0 = (u & 3) * 32;
    const u16* ap = Ab + (m0 + cr) * AP + g * 8;
    const u16* bp = WdT + (n0 + cr) * AP + g * 8;
    f32x16 acc = zf16();
#pragma unroll
    for (int k0 = 0; k0 < 128; k0 += 16)
      acc = MFMA32(ld8(ap + k0), ld8(bp + k0), acc);
#pragma unroll
    for (int i = 0; i < 16; ++i) {
      const int row = m0 + (i & 3) + 8 * (i >> 2) + 4 * g;
      Hs[row * AP + n0 + cr] = f2bu(acc[i]);
    }
  }
  __syncthreads();

  for (int rr = w; rr < 128; rr += 8) {
    const size_t grow = row0 + rr;
    const float h1 = bfr(Hs[rr * AP + l])      + bd[l]      + resid[grow * 128 + l];
    const float h2 = bfr(Hs[rr * AP + 64 + l]) + bd[64 + l] + resid[grow * 128 + 64 + l];
    const float mu = wsum(h1 + h2) * (1.0f / 128.0f);
    const float d1 = h1 - mu, d2 = h2 - mu;
    const float var = wsum(d1 * d1 + d2 * d2) * (1.0f / 128.0f);
    const float rs = rsqrtf(var + 1e-12f);
    out[grow * 128 + l]      = d1 * rs * lng[l]      + lnb[l];
    out[grow * 128 + 64 + l] = d2 * rs * lng[64 + l] + lnb[64 + l];
  }
}

}  // namespace

extern "C" void kernel_launch(void* const* d_in, const int* in_sizes, int n_in,
                              void* d_out, int out_size, void* d_ws,
                              size_t ws_size, hipStream_t stream) {
  (void)in_sizes; (void)n_in; (void)out_size;

  const float* input = (const float*)d_in[0];
  const float* attrT = (const float*)d_in[1];
  const float* posE  = (const float*)d_in[2];
  const float* mask  = (const float*)d_in[3];
  const float* Wq  = (const float*)d_in[4];  const float* bq  = (const float*)d_in[5];
  const float* Wk  = (const float*)d_in[6];  const float* bk  = (const float*)d_in[7];
  const float* Wv  = (const float*)d_in[8];  const float* bv  = (const float*)d_in[9];
  const float* Wqp = (const float*)d_in[10]; const float* bqp = (const float*)d_in[11];
  const float* Wkp = (const float*)d_in[12]; const float* bkp = (const float*)d_in[13];
  const float* Wqa = (const float*)d_in[14]; const float* bqa = (const float*)d_in[15];
  const float* Wka = (const float*)d_in[16]; const float* bka = (const float*)d_in[17];
  const float* W1  = (const float*)d_in[18]; const float* b1  = (const float*)d_in[19];
  const float* W2  = (const float*)d_in[20];
  const float* Wd  = (const float*)d_in[22]; const float* bd  = (const float*)d_in[23];
  const float* lng = (const float*)d_in[24]; const float* lnb = (const float*)d_in[25];

  float* ctx = (float*)d_out;  // d_out doubles as ctx staging, then final output

  if (ws_size >= WS_NEED) {
    u16* wsw = (u16*)d_ws;
    prep_weights<<<dim3(128), dim3(256), 0, stream>>>(
        Wq, Wk, Wqp, Wkp, Wv, Wqa, Wka, W1, Wd, wsw);
    attn_mega<true><<<dim3(B_ * 2), dim3(NTHR), 0, stream>>>(
        input, attrT, posE, mask, Wq, bq, Wk, bk, Wv, bv, Wqp, bqp, Wkp, bkp,
        Wqa, bqa, Wka, bka, W1, b1, W2, wsw, ctx);
    dense_ln<true><<<dim3(BS_ / 128), dim3(512), 0, stream>>>(
        ctx, Wd, bd, input, lng, lnb, wsw, ctx);
  } else {
    attn_mega<false><<<dim3(B_ * 2), dim3(NTHR), 0, stream>>>(
        input, attrT, posE, mask, Wq, bq, Wk, bk, Wv, bv, Wqp, bqp, Wkp, bkp,
        Wqa, bqa, Wka, bka, W1, b1, W2, nullptr, ctx);
    dense_ln<false><<<dim3(BS_ / 128), dim3(512), 0, stream>>>(
        ctx, Wd, bd, input, lng, lnb, nullptr, ctx);
  }
}